// Round 10
// baseline (305.012 us; speedup 1.0000x reference)
//
#include <hip/hip_runtime.h>
#include <hip/hip_bf16.h>
#include <cstdint>

#define N_NODES 50000
#define N_EDGES 800000
#define GENE    256
#define HID     128
#define FEAT    64
#define NCHUNK  98
#define KC      512

typedef __attribute__((ext_vector_type(8))) short bf16x8;
typedef __attribute__((ext_vector_type(4))) float f32x4;
typedef unsigned short u16;
typedef unsigned int u32;

__device__ __forceinline__ u16 f2b(float f) {
  __hip_bfloat16 h = __float2bfloat16(f);
  return *reinterpret_cast<u16*>(&h);
}
__device__ __forceinline__ float b2f(u16 u) {
  return __uint_as_float(((unsigned)u) << 16);
}
__device__ __forceinline__ float b2f_lo(u32 u) { return __uint_as_float(u << 16); }
__device__ __forceinline__ float b2f_hi(u32 u) { return __uint_as_float(u & 0xffff0000u); }

__device__ __forceinline__ bf16x8 cvt8(float4 f0, float4 f1) {
  bf16x8 a;
  a[0] = (short)f2b(f0.x); a[1] = (short)f2b(f0.y);
  a[2] = (short)f2b(f0.z); a[3] = (short)f2b(f0.w);
  a[4] = (short)f2b(f1.x); a[5] = (short)f2b(f1.y);
  a[6] = (short)f2b(f1.z); a[7] = (short)f2b(f1.w);
  return a;
}

// ---------------- prep: zero deg + build Wt1/Wt2 (bf16 transposed) ----------------

__global__ void k_prep(int* __restrict__ deg,
                       const float* __restrict__ W1, u16* __restrict__ Wt1,
                       const float* __restrict__ W2, u16* __restrict__ Wt2) {
  int i = blockIdx.x * 256 + threadIdx.x;
  if (i < N_NODES) deg[i] = 0;
  int j = i - N_NODES;
  if (j >= 0 && j < HID * GENE) {
    int n = j / GENE, k = j % GENE;
    Wt1[j] = f2b(W1[(size_t)k * HID + n]);
  }
  int j2 = j - HID * GENE;
  if (j2 >= 0 && j2 < FEAT * HID) {
    int n = j2 / HID, k = j2 % HID;
    Wt2[j2] = f2b(W2[(size_t)k * FEAT + n]);
  }
}

// ---------------- degree / CSR build ----------------

__global__ void k_deg(const int* __restrict__ dst, int* __restrict__ deg) {
  int e4 = blockIdx.x * blockDim.x + threadIdx.x;
  if (e4 * 4 < N_EDGES) {
    int4 d = *(const int4*)(dst + e4 * 4);
    atomicAdd(&deg[d.x], 1);
    atomicAdd(&deg[d.y], 1);
    atomicAdd(&deg[d.z], 1);
    atomicAdd(&deg[d.w], 1);
  }
}

__global__ void k_scan1(const int* __restrict__ deg, int* __restrict__ bsum) {
  __shared__ int s[512];
  int t = threadIdx.x;
  int i = blockIdx.x * 512 + t;
  s[t] = (i < N_NODES) ? deg[i] : 0;
  __syncthreads();
  for (int off = 256; off > 0; off >>= 1) {
    if (t < off) s[t] += s[t + off];
    __syncthreads();
  }
  if (t == 0) bsum[blockIdx.x] = s[0];
}

__global__ void k_scan2(int* bsum, int nb) {
  __shared__ int s[128];
  int t = threadIdx.x;
  int v = (t < nb) ? bsum[t] : 0;
  s[t] = v;
  __syncthreads();
  for (int off = 1; off < 128; off <<= 1) {
    int add = (t >= off) ? s[t - off] : 0;
    __syncthreads();
    s[t] += add;
    __syncthreads();
  }
  if (t < nb) bsum[t] = s[t] - v;  // exclusive
}

// scan3 also computes dinv and initializes cursor = row_ptr (saves a random
// row_ptr read per edge in k_fill)
__global__ void k_scan3(const int* __restrict__ deg, const int* __restrict__ bsum,
                        int* __restrict__ row_ptr, int* __restrict__ cur,
                        float* __restrict__ dinv) {
  __shared__ int s[512];
  int t = threadIdx.x;
  int i = blockIdx.x * 512 + t;
  int v = (i < N_NODES) ? deg[i] : 0;
  s[t] = v;
  __syncthreads();
  for (int off = 1; off < 512; off <<= 1) {
    int add = (t >= off) ? s[t - off] : 0;
    __syncthreads();
    s[t] += add;
    __syncthreads();
  }
  int incl = s[t] + bsum[blockIdx.x];
  if (i < N_NODES) {
    int rp = incl - v;
    row_ptr[i] = rp;
    cur[i] = rp;
    dinv[i] = rsqrtf((float)(v + 1));
  }
  if (i == N_NODES - 1) row_ptr[N_NODES] = incl;
}

__global__ void k_fill(const int* __restrict__ src, const int* __restrict__ dst,
                       int* __restrict__ cur, int* __restrict__ col) {
  int e4 = blockIdx.x * blockDim.x + threadIdx.x;
  if (e4 * 4 < N_EDGES) {
    int4 d = *(const int4*)(dst + e4 * 4);
    int4 s = *(const int4*)(src + e4 * 4);
    col[atomicAdd(&cur[d.x], 1)] = s.x;
    col[atomicAdd(&cur[d.y], 1)] = s.y;
    col[atomicAdd(&cur[d.z], 1)] = s.z;
    col[atomicAdd(&cur[d.w], 1)] = s.w;
  }
}

// ---- LDS-staged MFMA GEMM: Y[m] = dinv[m]*(X[m] @ W).
// QUART: output layout [4][N_NODES][32] u16 (feature quarters) for L2-fit agg. ----

template<bool F32IN, int NN, int KK, bool QUART>
__global__ __launch_bounds__(256) void gemm_lds(const void* __restrict__ Xv,
                                                const u16* __restrict__ Wt,
                                                const float* __restrict__ dinv,
                                                u16* __restrict__ Y) {
  constexpr int NF = NN / 32;
  constexpr int KU = KK / 8;
  constexpr int UPT = NN * KK / 8 / 256;
  __shared__ u16 wlds[NN * KK];

  int t = threadIdx.x;
  int w = t >> 6, l = t & 63;
  int lm = l & 15, lg = l >> 4;
  int rowhalf = w >> 1, colhalf = w & 1;
  int m0 = blockIdx.x * 64;
  int cb = colhalf * (NN / 2);

#pragma unroll
  for (int i = 0; i < UPT; ++i) {
    int j = t + i * 256;
    int row = j / KU, u = j - row * KU;
    bf16x8 v = *(const bf16x8*)(Wt + j * 8);
    *(bf16x8*)((char*)wlds + row * (KK * 2) + ((u * 16) ^ ((row & 7) << 4))) = v;
  }
  __syncthreads();

  int ra0 = m0 + rowhalf * 32 + lm;
  int ra1 = ra0 + 16;
  int rs0 = (ra0 < N_NODES) ? ra0 : 0;
  int rs1 = (ra1 < N_NODES) ? ra1 : 0;

  f32x4 acc[2][NF] = {};
#pragma unroll
  for (int k0 = 0; k0 < KK; k0 += 32) {
    bf16x8 a0, a1;
    if constexpr (F32IN) {
      const float* x0 = (const float*)Xv + (size_t)rs0 * KK + k0 + lg * 8;
      const float* x1 = (const float*)Xv + (size_t)rs1 * KK + k0 + lg * 8;
      a0 = cvt8(*(const float4*)x0, *(const float4*)(x0 + 4));
      a1 = cvt8(*(const float4*)x1, *(const float4*)(x1 + 4));
    } else {
      a0 = *(const bf16x8*)((const u16*)Xv + (size_t)rs0 * KK + k0 + lg * 8);
      a1 = *(const bf16x8*)((const u16*)Xv + (size_t)rs1 * KK + k0 + lg * 8);
    }
#pragma unroll
    for (int f = 0; f < NF; ++f) {
      int row = cb + f * 16 + lm;
      bf16x8 b = *(const bf16x8*)((char*)wlds + row * (KK * 2) +
                                  (((k0 + lg * 8) * 2) ^ ((row & 7) << 4)));
      acc[0][f] = __builtin_amdgcn_mfma_f32_16x16x32_bf16(a0, b, acc[0][f], 0, 0, 0);
      acc[1][f] = __builtin_amdgcn_mfma_f32_16x16x32_bf16(a1, b, acc[1][f], 0, 0, 0);
    }
  }
#pragma unroll
  for (int rf = 0; rf < 2; ++rf) {
    int mo = m0 + rowhalf * 32 + rf * 16 + lg * 4;
#pragma unroll
    for (int r = 0; r < 4; ++r) {
      int mm = mo + r;
      if (mm < N_NODES) {
        float dv = dinv[mm];
#pragma unroll
        for (int f = 0; f < NF; ++f) {
          int colx = cb + f * 16 + lm;
          u16 val = f2b(acc[rf][f][r] * dv);
          if constexpr (QUART)
            Y[(size_t)(colx >> 5) * (N_NODES * 32) + (size_t)mm * 32 + (colx & 31)] = val;
          else
            Y[(size_t)mm * NN + colx] = val;
        }
      }
    }
  }
}

// ---- agg HID=128, quartered: pass q reads Aq[q] (3.2MB, per-XCD-L2-resident).
// 16-lane group per node: gathers are 64B contiguous. grid (3125, 4). ----

__global__ __launch_bounds__(256) void k_agg128q(
    const u32* __restrict__ Aq, const float* __restrict__ dinv,
    const int* __restrict__ row_ptr, const int* __restrict__ col,
    const float* __restrict__ bias, u32* __restrict__ out) {
  int t = threadIdx.x;
  int w = t >> 6, l = t & 63;
  int g = l >> 4, ll = l & 15;
  int node = blockIdx.x * 16 + w * 4 + g;
  int q = blockIdx.y;
  const u32* Ab = Aq + (size_t)q * (N_NODES * 16);
  float2 bv = *(const float2*)(bias + q * 32 + 2 * ll);

  float di = dinv[node];
  int beg = row_ptr[node], end = row_ptr[node + 1];
  u32 us = Ab[(size_t)node * 16 + ll];
  float ax = b2f_lo(us), ay = b2f_hi(us);
  int r = beg;
  for (; r + 4 <= end; r += 4) {
    int s0 = __builtin_nontemporal_load(col + r);
    int s1 = __builtin_nontemporal_load(col + r + 1);
    int s2 = __builtin_nontemporal_load(col + r + 2);
    int s3 = __builtin_nontemporal_load(col + r + 3);
    u32 u0 = Ab[(size_t)s0 * 16 + ll];
    u32 u1 = Ab[(size_t)s1 * 16 + ll];
    u32 u2 = Ab[(size_t)s2 * 16 + ll];
    u32 u3 = Ab[(size_t)s3 * 16 + ll];
    ax += (b2f_lo(u0) + b2f_lo(u1)) + (b2f_lo(u2) + b2f_lo(u3));
    ay += (b2f_hi(u0) + b2f_hi(u1)) + (b2f_hi(u2) + b2f_hi(u3));
  }
  for (; r < end; ++r) {
    u32 u0 = Ab[(size_t)__builtin_nontemporal_load(col + r) * 16 + ll];
    ax += b2f_lo(u0); ay += b2f_hi(u0);
  }
  float vx = fmaxf(bv.x + di * ax, 0.f);
  float vy = fmaxf(bv.y + di * ay, 0.f);
  out[(size_t)node * 64 + q * 16 + ll] = ((u32)f2b(vy) << 16) | (u32)f2b(vx);
}

// ---- agg FEAT=64: u16 loads, 1 wave/node, 4 nodes/block ----

__global__ __launch_bounds__(256) void k_agg64(
    const u16* __restrict__ Ain, const float* __restrict__ dinv,
    const int* __restrict__ row_ptr, const int* __restrict__ col,
    const float* __restrict__ bias, u16* __restrict__ out) {
  int t = threadIdx.x;
  int node = blockIdx.x * 4 + (t >> 6);
  int f = t & 63;
  float bf = bias[f];

  float di = dinv[node];
  int beg = row_ptr[node], end = row_ptr[node + 1];
  float acc = b2f(Ain[(size_t)node * 64 + f]);
  int r = beg;
  for (; r + 4 <= end; r += 4) {
    int s0 = __builtin_nontemporal_load(col + r);
    int s1 = __builtin_nontemporal_load(col + r + 1);
    int s2 = __builtin_nontemporal_load(col + r + 2);
    int s3 = __builtin_nontemporal_load(col + r + 3);
    float a0 = b2f(Ain[(size_t)s0 * 64 + f]);
    float a1 = b2f(Ain[(size_t)s1 * 64 + f]);
    float a2 = b2f(Ain[(size_t)s2 * 64 + f]);
    float a3 = b2f(Ain[(size_t)s3 * 64 + f]);
    acc += (a0 + a1) + (a2 + a3);
  }
  for (; r < end; ++r)
    acc += b2f(Ain[(size_t)__builtin_nontemporal_load(col + r) * 64 + f]);
  out[(size_t)node * 64 + f] = f2b(bf + di * acc);
}

// ---------------- transpose h2 -> h2t ----------------

__global__ __launch_bounds__(256) void k_tr(const u16* __restrict__ h2,
                                            u16* __restrict__ h2t) {
  __shared__ u16 tile[64][65];
  int i0 = blockIdx.x * 64;
  int t = threadIdx.x;
  int r = t >> 2, c0 = (t & 3) * 16;
  int i = i0 + r;
#pragma unroll
  for (int j = 0; j < 16; ++j)
    tile[r][c0 + j] = (i < N_NODES) ? h2[(size_t)i * 64 + c0 + j] : (u16)0;
  __syncthreads();
  int io = t & 63, n0 = (t >> 6) * 16;
  int i2 = i0 + io;
  if (i2 < N_NODES) {
#pragma unroll
    for (int j = 0; j < 16; ++j)
      h2t[(size_t)(n0 + j) * N_NODES + i2] = tile[io][n0 + j];
  }
}

// ---- final: B-chunk (KC=512) in LDS (64KB, XOR-swizzled, zero-padded);
//      A streamed with unroll-4 (8 loads in flight/wave). ----

__global__ __launch_bounds__(256) void final_mfma(const float* __restrict__ data,
                                                  const u16* __restrict__ h2t,
                                                  float* __restrict__ partial) {
  constexpr int KU = KC / 8;
  __shared__ u16 blds[64 * KC];  // 64 KB

  int t = threadIdx.x;
  int w = t >> 6, l = t & 63;
  int lm = l & 15, lg = l >> 4;
  int kc0 = blockIdx.y * KC;
  int klen = N_NODES - kc0; if (klen > KC) klen = KC;

#pragma unroll
  for (int i = 0; i < 64 * KU / 256; ++i) {
    int j = t + i * 256;
    int row = j / KU, u = j - row * KU;
    int kpos = kc0 + u * 8;
    bf16x8 v = {};
    if (kpos + 8 <= N_NODES) v = *(const bf16x8*)(h2t + (size_t)row * N_NODES + kpos);
    *(bf16x8*)((char*)blds + row * (KC * 2) + ((u * 16) ^ ((row & 7) << 4))) = v;
  }
  __syncthreads();

  int m = blockIdx.x * 64 + w * 16 + lm;
  const float* drow = data + (size_t)m * N_NODES + kc0 + lg * 8;
  f32x4 acc[4] = {};

  auto bload = [&](int koff, int f) -> bf16x8 {
    int row = f * 16 + lm;
    return *(const bf16x8*)((char*)blds + row * (KC * 2) +
                            ((koff * 2) ^ ((row & 7) << 4)));
  };

  int kk = 0;
  for (; kk + 128 <= klen; kk += 128) {
    float4 fa[4][2];
#pragma unroll
    for (int s = 0; s < 4; ++s) {
      fa[s][0] = *(const float4*)(drow + kk + s * 32);
      fa[s][1] = *(const float4*)(drow + kk + s * 32 + 4);
    }
#pragma unroll
    for (int s = 0; s < 4; ++s) {
      bf16x8 a = cvt8(fa[s][0], fa[s][1]);
#pragma unroll
      for (int f = 0; f < 4; ++f)
        acc[f] = __builtin_amdgcn_mfma_f32_16x16x32_bf16(a, bload(kk + s * 32 + lg * 8, f), acc[f], 0, 0, 0);
    }
  }
  for (; kk + 32 <= klen; kk += 32) {
    bf16x8 a = cvt8(*(const float4*)(drow + kk), *(const float4*)(drow + kk + 4));
#pragma unroll
    for (int f = 0; f < 4; ++f)
      acc[f] = __builtin_amdgcn_mfma_f32_16x16x32_bf16(a, bload(kk + lg * 8, f), acc[f], 0, 0, 0);
  }
  if (kk < klen) {
    bool ok = (kk + lg * 8 + 8) <= klen;
    bf16x8 a = {};
    if (ok) a = cvt8(*(const float4*)(drow + kk), *(const float4*)(drow + kk + 4));
#pragma unroll
    for (int f = 0; f < 4; ++f)
      acc[f] = __builtin_amdgcn_mfma_f32_16x16x32_bf16(a, bload(kk + lg * 8, f), acc[f], 0, 0, 0);
  }

  float* pout = partial + (size_t)blockIdx.y * (1024 * FEAT);
  int mo = blockIdx.x * 64 + w * 16 + lg * 4;
#pragma unroll
  for (int f = 0; f < 4; ++f)
#pragma unroll
    for (int r = 0; r < 4; ++r)
      pout[(size_t)(mo + r) * FEAT + f * 16 + lm] = acc[f][r];
}

__global__ __launch_bounds__(256) void k_red(const float* __restrict__ partial,
                                             float* __restrict__ out) {
  int i = blockIdx.x * 256 + threadIdx.x;  // 16384 float4 outputs
  f32x4 s = {};
#pragma unroll
  for (int c = 0; c < NCHUNK; ++c)
    s += *(const f32x4*)(partial + (size_t)c * (1024 * FEAT) + i * 4);
  *(f32x4*)((float*)out + i * 4) = s;
}

// ---------------- launch ----------------

extern "C" void kernel_launch(void* const* d_in, const int* in_sizes, int n_in,
                              void* d_out, int out_size, void* d_ws, size_t ws_size,
                              hipStream_t stream) {
  const float* data = (const float*)d_in[0];
  const float* x    = (const float*)d_in[1];
  const int*   ei   = (const int*)d_in[2];
  const float* W1   = (const float*)d_in[3];
  const float* b1   = (const float*)d_in[4];
  const float* W2   = (const float*)d_in[5];
  const float* b2   = (const float*)d_in[6];
  float* out = (float*)d_out;

  char* ws = (char*)d_ws;
  u16*   A    = (u16*)(ws + 0);            // 12.8 MB (quartered in layer1, flat in layer2)
  u16*   Hb   = (u16*)(ws + 12800000);     // 12.8 MB
  u16*   h2t  = (u16*)(ws + 25690112);     // 6.4 MB
  u16*   Wt1  = (u16*)(ws + 32090112);
  u16*   Wt2  = (u16*)(ws + 32155648);
  int*   deg  = (int*)(ws + 32172032);
  int*   rowp = (int*)(ws + 32372032);
  int*   cur  = (int*)(ws + 32572048);
  int*   bsum = (int*)(ws + 32772048);
  float* dinv = (float*)(ws + 32772560);
  int*   col  = (int*)(ws + 32972560);     // 3.2 MB
  float* part = (float*)(ws + 36200448);   // 98x1024x64 f32 = 25.7 MB

  const int* srcp = ei;
  const int* dstp = ei + N_EDGES;

  k_prep<<<(N_NODES + HID * GENE + FEAT * HID + 255) / 256, 256, 0, stream>>>(
      deg, W1, Wt1, W2, Wt2);
  k_deg<<<(N_EDGES / 4 + 255) / 256, 256, 0, stream>>>(dstp, deg);
  int nb = (N_NODES + 511) / 512;  // 98
  k_scan1<<<nb, 512, 0, stream>>>(deg, bsum);
  k_scan2<<<1, 128, 0, stream>>>(bsum, nb);
  k_scan3<<<nb, 512, 0, stream>>>(deg, bsum, rowp, cur, dinv);
  k_fill<<<(N_EDGES / 4 + 255) / 256, 256, 0, stream>>>(srcp, dstp, cur, col);

  // layer 1: quartered intermediate for L2-resident gathers
  gemm_lds<true, HID, GENE, true><<<(N_NODES + 63) / 64, 256, 0, stream>>>(x, Wt1, dinv, A);
  k_agg128q<<<dim3(N_NODES / 16, 4), 256, 0, stream>>>((const u32*)A, dinv, rowp, col, b1, (u32*)Hb);

  // layer 2
  gemm_lds<false, FEAT, HID, false><<<(N_NODES + 63) / 64, 256, 0, stream>>>(Hb, Wt2, dinv, A);
  k_agg64<<<N_NODES / 4, 256, 0, stream>>>(A, dinv, rowp, col, b2, Hb);

  k_tr<<<(N_NODES + 63) / 64, 256, 0, stream>>>(Hb, h2t);

  final_mfma<<<dim3(16, NCHUNK), 256, 0, stream>>>(data, h2t, part);
  k_red<<<(1024 * FEAT) / 4 / 256, 256, 0, stream>>>(part, out);
}

// Round 11
// 274.945 us; speedup vs baseline: 1.1094x; 1.1094x over previous
//
#include <hip/hip_runtime.h>
#include <hip/hip_bf16.h>
#include <cstdint>

#define N_NODES 50000
#define N_EDGES 800000
#define GENE    256
#define HID     128
#define FEAT    64
#define NCHUNK  196
#define KC      256

typedef __attribute__((ext_vector_type(8))) short bf16x8;
typedef __attribute__((ext_vector_type(4))) float f32x4;
typedef unsigned short u16;
typedef unsigned int u32;

__device__ __forceinline__ u16 f2b(float f) {
  __hip_bfloat16 h = __float2bfloat16(f);
  return *reinterpret_cast<u16*>(&h);
}
__device__ __forceinline__ float b2f(u16 u) {
  return __uint_as_float(((unsigned)u) << 16);
}
__device__ __forceinline__ float b2f_lo(u32 u) { return __uint_as_float(u << 16); }
__device__ __forceinline__ float b2f_hi(u32 u) { return __uint_as_float(u & 0xffff0000u); }

__device__ __forceinline__ bf16x8 cvt8(float4 f0, float4 f1) {
  bf16x8 a;
  a[0] = (short)f2b(f0.x); a[1] = (short)f2b(f0.y);
  a[2] = (short)f2b(f0.z); a[3] = (short)f2b(f0.w);
  a[4] = (short)f2b(f1.x); a[5] = (short)f2b(f1.y);
  a[6] = (short)f2b(f1.z); a[7] = (short)f2b(f1.w);
  return a;
}

// ---------------- prep: zero deg + build Wt1/Wt2 (bf16 transposed) ----------------

__global__ void k_prep(int* __restrict__ deg,
                       const float* __restrict__ W1, u16* __restrict__ Wt1,
                       const float* __restrict__ W2, u16* __restrict__ Wt2) {
  int i = blockIdx.x * 256 + threadIdx.x;
  if (i < N_NODES) deg[i] = 0;
  int j = i - N_NODES;
  if (j >= 0 && j < HID * GENE) {
    int n = j / GENE, k = j % GENE;
    Wt1[j] = f2b(W1[(size_t)k * HID + n]);
  }
  int j2 = j - HID * GENE;
  if (j2 >= 0 && j2 < FEAT * HID) {
    int n = j2 / HID, k = j2 % HID;
    Wt2[j2] = f2b(W2[(size_t)k * FEAT + n]);
  }
}

// ---------------- degree / CSR build ----------------

__global__ void k_deg(const int* __restrict__ dst, int* __restrict__ deg) {
  int e4 = blockIdx.x * blockDim.x + threadIdx.x;
  if (e4 * 4 < N_EDGES) {
    int4 d = *(const int4*)(dst + e4 * 4);
    atomicAdd(&deg[d.x], 1);
    atomicAdd(&deg[d.y], 1);
    atomicAdd(&deg[d.z], 1);
    atomicAdd(&deg[d.w], 1);
  }
}

__global__ void k_scan1(const int* __restrict__ deg, int* __restrict__ bsum) {
  __shared__ int s[512];
  int t = threadIdx.x;
  int i = blockIdx.x * 512 + t;
  s[t] = (i < N_NODES) ? deg[i] : 0;
  __syncthreads();
  for (int off = 256; off > 0; off >>= 1) {
    if (t < off) s[t] += s[t + off];
    __syncthreads();
  }
  if (t == 0) bsum[blockIdx.x] = s[0];
}

__global__ void k_scan2(int* bsum, int nb) {
  __shared__ int s[128];
  int t = threadIdx.x;
  int v = (t < nb) ? bsum[t] : 0;
  s[t] = v;
  __syncthreads();
  for (int off = 1; off < 128; off <<= 1) {
    int add = (t >= off) ? s[t - off] : 0;
    __syncthreads();
    s[t] += add;
    __syncthreads();
  }
  if (t < nb) bsum[t] = s[t] - v;  // exclusive
}

// scan3: row_ptr, dinv, and cursor = row_ptr (k_fill then needs no rowp read)
__global__ void k_scan3(const int* __restrict__ deg, const int* __restrict__ bsum,
                        int* __restrict__ row_ptr, int* __restrict__ cur,
                        float* __restrict__ dinv) {
  __shared__ int s[512];
  int t = threadIdx.x;
  int i = blockIdx.x * 512 + t;
  int v = (i < N_NODES) ? deg[i] : 0;
  s[t] = v;
  __syncthreads();
  for (int off = 1; off < 512; off <<= 1) {
    int add = (t >= off) ? s[t - off] : 0;
    __syncthreads();
    s[t] += add;
    __syncthreads();
  }
  int incl = s[t] + bsum[blockIdx.x];
  if (i < N_NODES) {
    int rp = incl - v;
    row_ptr[i] = rp;
    cur[i] = rp;
    dinv[i] = rsqrtf((float)(v + 1));
  }
  if (i == N_NODES - 1) row_ptr[N_NODES] = incl;
}

__global__ void k_fill(const int* __restrict__ src, const int* __restrict__ dst,
                       int* __restrict__ cur, int* __restrict__ col) {
  int e4 = blockIdx.x * blockDim.x + threadIdx.x;
  if (e4 * 4 < N_EDGES) {
    int4 d = *(const int4*)(dst + e4 * 4);
    int4 s = *(const int4*)(src + e4 * 4);
    col[atomicAdd(&cur[d.x], 1)] = s.x;
    col[atomicAdd(&cur[d.y], 1)] = s.y;
    col[atomicAdd(&cur[d.z], 1)] = s.z;
    col[atomicAdd(&cur[d.w], 1)] = s.w;
  }
}

// ---- LDS-staged MFMA GEMM: Y[m] = dinv[m]*(X[m] @ W). ----

template<bool F32IN, int NN, int KK>
__global__ __launch_bounds__(256) void gemm_lds(const void* __restrict__ Xv,
                                                const u16* __restrict__ Wt,
                                                const float* __restrict__ dinv,
                                                u16* __restrict__ Y) {
  constexpr int NF = NN / 32;
  constexpr int KU = KK / 8;
  constexpr int UPT = NN * KK / 8 / 256;
  __shared__ u16 wlds[NN * KK];

  int t = threadIdx.x;
  int w = t >> 6, l = t & 63;
  int lm = l & 15, lg = l >> 4;
  int rowhalf = w >> 1, colhalf = w & 1;
  int m0 = blockIdx.x * 64;
  int cb = colhalf * (NN / 2);

#pragma unroll
  for (int i = 0; i < UPT; ++i) {
    int j = t + i * 256;
    int row = j / KU, u = j - row * KU;
    bf16x8 v = *(const bf16x8*)(Wt + j * 8);
    *(bf16x8*)((char*)wlds + row * (KK * 2) + ((u * 16) ^ ((row & 7) << 4))) = v;
  }
  __syncthreads();

  int ra0 = m0 + rowhalf * 32 + lm;
  int ra1 = ra0 + 16;
  int rs0 = (ra0 < N_NODES) ? ra0 : 0;
  int rs1 = (ra1 < N_NODES) ? ra1 : 0;

  f32x4 acc[2][NF] = {};
#pragma unroll
  for (int k0 = 0; k0 < KK; k0 += 32) {
    bf16x8 a0, a1;
    if constexpr (F32IN) {
      const float* x0 = (const float*)Xv + (size_t)rs0 * KK + k0 + lg * 8;
      const float* x1 = (const float*)Xv + (size_t)rs1 * KK + k0 + lg * 8;
      a0 = cvt8(*(const float4*)x0, *(const float4*)(x0 + 4));
      a1 = cvt8(*(const float4*)x1, *(const float4*)(x1 + 4));
    } else {
      a0 = *(const bf16x8*)((const u16*)Xv + (size_t)rs0 * KK + k0 + lg * 8);
      a1 = *(const bf16x8*)((const u16*)Xv + (size_t)rs1 * KK + k0 + lg * 8);
    }
#pragma unroll
    for (int f = 0; f < NF; ++f) {
      int row = cb + f * 16 + lm;
      bf16x8 b = *(const bf16x8*)((char*)wlds + row * (KK * 2) +
                                  (((k0 + lg * 8) * 2) ^ ((row & 7) << 4)));
      acc[0][f] = __builtin_amdgcn_mfma_f32_16x16x32_bf16(a0, b, acc[0][f], 0, 0, 0);
      acc[1][f] = __builtin_amdgcn_mfma_f32_16x16x32_bf16(a1, b, acc[1][f], 0, 0, 0);
    }
  }
#pragma unroll
  for (int rf = 0; rf < 2; ++rf) {
    int mo = m0 + rowhalf * 32 + rf * 16 + lg * 4;
#pragma unroll
    for (int r = 0; r < 4; ++r) {
      int mm = mo + r;
      if (mm < N_NODES) {
        float dv = dinv[mm];
#pragma unroll
        for (int f = 0; f < NF; ++f)
          Y[(size_t)mm * NN + cb + f * 16 + lm] = f2b(acc[rf][f][r] * dv);
      }
    }
  }
}

// ---- agg HID=128: u32 loads, 1 wave/node, 4 nodes/block ----

__global__ __launch_bounds__(256) void k_agg128(
    const u32* __restrict__ Ain, const float* __restrict__ dinv,
    const int* __restrict__ row_ptr, const int* __restrict__ col,
    const float* __restrict__ bias, u32* __restrict__ out) {
  int t = threadIdx.x;
  int node = blockIdx.x * 4 + (t >> 6);
  int l = t & 63;
  float2 bv = *(const float2*)(bias + 2 * l);

  float di = dinv[node];
  int beg = row_ptr[node], end = row_ptr[node + 1];
  u32 us = Ain[(size_t)node * 64 + l];
  float ax = b2f_lo(us), ay = b2f_hi(us);
  int r = beg;
  for (; r + 4 <= end; r += 4) {
    int s0 = col[r], s1 = col[r + 1], s2 = col[r + 2], s3 = col[r + 3];
    u32 u0 = Ain[(size_t)s0 * 64 + l];
    u32 u1 = Ain[(size_t)s1 * 64 + l];
    u32 u2 = Ain[(size_t)s2 * 64 + l];
    u32 u3 = Ain[(size_t)s3 * 64 + l];
    ax += (b2f_lo(u0) + b2f_lo(u1)) + (b2f_lo(u2) + b2f_lo(u3));
    ay += (b2f_hi(u0) + b2f_hi(u1)) + (b2f_hi(u2) + b2f_hi(u3));
  }
  for (; r < end; ++r) {
    u32 u0 = Ain[(size_t)col[r] * 64 + l];
    ax += b2f_lo(u0); ay += b2f_hi(u0);
  }
  float vx = fmaxf(bv.x + di * ax, 0.f);
  float vy = fmaxf(bv.y + di * ay, 0.f);
  out[(size_t)node * 64 + l] = ((u32)f2b(vy) << 16) | (u32)f2b(vx);
}

// ---- agg FEAT=64: u16 loads, 1 wave/node, 4 nodes/block ----

__global__ __launch_bounds__(256) void k_agg64(
    const u16* __restrict__ Ain, const float* __restrict__ dinv,
    const int* __restrict__ row_ptr, const int* __restrict__ col,
    const float* __restrict__ bias, u16* __restrict__ out) {
  int t = threadIdx.x;
  int node = blockIdx.x * 4 + (t >> 6);
  int f = t & 63;
  float bf = bias[f];

  float di = dinv[node];
  int beg = row_ptr[node], end = row_ptr[node + 1];
  float acc = b2f(Ain[(size_t)node * 64 + f]);
  int r = beg;
  for (; r + 4 <= end; r += 4) {
    int s0 = col[r], s1 = col[r + 1], s2 = col[r + 2], s3 = col[r + 3];
    float a0 = b2f(Ain[(size_t)s0 * 64 + f]);
    float a1 = b2f(Ain[(size_t)s1 * 64 + f]);
    float a2 = b2f(Ain[(size_t)s2 * 64 + f]);
    float a3 = b2f(Ain[(size_t)s3 * 64 + f]);
    acc += (a0 + a1) + (a2 + a3);
  }
  for (; r < end; ++r) acc += b2f(Ain[(size_t)col[r] * 64 + f]);
  out[(size_t)node * 64 + f] = f2b(bf + di * acc);
}

// ---------------- transpose h2 -> h2t ----------------

__global__ __launch_bounds__(256) void k_tr(const u16* __restrict__ h2,
                                            u16* __restrict__ h2t) {
  __shared__ u16 tile[64][65];
  int i0 = blockIdx.x * 64;
  int t = threadIdx.x;
  int r = t >> 2, c0 = (t & 3) * 16;
  int i = i0 + r;
#pragma unroll
  for (int j = 0; j < 16; ++j)
    tile[r][c0 + j] = (i < N_NODES) ? h2[(size_t)i * 64 + c0 + j] : (u16)0;
  __syncthreads();
  int io = t & 63, n0 = (t >> 6) * 16;
  int i2 = i0 + io;
  if (i2 < N_NODES) {
#pragma unroll
    for (int j = 0; j < 16; ++j)
      h2t[(size_t)(n0 + j) * N_NODES + i2] = tile[io][n0 + j];
  }
}

// ---- final: B-chunk (KC=256) in LDS (32KB, XOR-swizzled, zero-padded);
//      A streamed with unroll-4 (8 loads in flight/wave). ----

__global__ __launch_bounds__(256) void final_mfma(const float* __restrict__ data,
                                                  const u16* __restrict__ h2t,
                                                  float* __restrict__ partial) {
  constexpr int KU = KC / 8;
  __shared__ u16 blds[64 * KC];  // 32 KB

  int t = threadIdx.x;
  int w = t >> 6, l = t & 63;
  int lm = l & 15, lg = l >> 4;
  int kc0 = blockIdx.y * KC;
  int klen = N_NODES - kc0; if (klen > KC) klen = KC;

#pragma unroll
  for (int i = 0; i < 64 * KU / 256; ++i) {
    int j = t + i * 256;
    int row = j / KU, u = j - row * KU;
    int kpos = kc0 + u * 8;
    bf16x8 v = {};
    if (kpos + 8 <= N_NODES) v = *(const bf16x8*)(h2t + (size_t)row * N_NODES + kpos);
    *(bf16x8*)((char*)blds + row * (KC * 2) + ((u * 16) ^ ((row & 7) << 4))) = v;
  }
  __syncthreads();

  int m = blockIdx.x * 64 + w * 16 + lm;
  const float* drow = data + (size_t)m * N_NODES + kc0 + lg * 8;
  f32x4 acc[4] = {};

  auto bload = [&](int koff, int f) -> bf16x8 {
    int row = f * 16 + lm;
    return *(const bf16x8*)((char*)blds + row * (KC * 2) +
                            ((koff * 2) ^ ((row & 7) << 4)));
  };

  int kk = 0;
  for (; kk + 128 <= klen; kk += 128) {
    float4 fa[4][2];
#pragma unroll
    for (int s = 0; s < 4; ++s) {
      fa[s][0] = *(const float4*)(drow + kk + s * 32);
      fa[s][1] = *(const float4*)(drow + kk + s * 32 + 4);
    }
#pragma unroll
    for (int s = 0; s < 4; ++s) {
      bf16x8 a = cvt8(fa[s][0], fa[s][1]);
#pragma unroll
      for (int f = 0; f < 4; ++f)
        acc[f] = __builtin_amdgcn_mfma_f32_16x16x32_bf16(a, bload(kk + s * 32 + lg * 8, f), acc[f], 0, 0, 0);
    }
  }
  for (; kk + 32 <= klen; kk += 32) {
    bf16x8 a = cvt8(*(const float4*)(drow + kk), *(const float4*)(drow + kk + 4));
#pragma unroll
    for (int f = 0; f < 4; ++f)
      acc[f] = __builtin_amdgcn_mfma_f32_16x16x32_bf16(a, bload(kk + lg * 8, f), acc[f], 0, 0, 0);
  }
  if (kk < klen) {
    bool ok = (kk + lg * 8 + 8) <= klen;
    bf16x8 a = {};
    if (ok) a = cvt8(*(const float4*)(drow + kk), *(const float4*)(drow + kk + 4));
#pragma unroll
    for (int f = 0; f < 4; ++f)
      acc[f] = __builtin_amdgcn_mfma_f32_16x16x32_bf16(a, bload(kk + lg * 8, f), acc[f], 0, 0, 0);
  }

  float* pout = partial + (size_t)blockIdx.y * (1024 * FEAT);
  int mo = blockIdx.x * 64 + w * 16 + lg * 4;
#pragma unroll
  for (int f = 0; f < 4; ++f)
#pragma unroll
    for (int r = 0; r < 4; ++r)
      pout[(size_t)(mo + r) * FEAT + f * 16 + lm] = acc[f][r];
}

__global__ __launch_bounds__(256) void k_red(const float* __restrict__ partial,
                                             float* __restrict__ out) {
  int i = blockIdx.x * 256 + threadIdx.x;  // 16384 float4 outputs
  f32x4 s = {};
#pragma unroll
  for (int c = 0; c < NCHUNK; ++c)
    s += *(const f32x4*)(partial + (size_t)c * (1024 * FEAT) + i * 4);
  *(f32x4*)((float*)out + i * 4) = s;
}

// ---------------- launch ----------------

extern "C" void kernel_launch(void* const* d_in, const int* in_sizes, int n_in,
                              void* d_out, int out_size, void* d_ws, size_t ws_size,
                              hipStream_t stream) {
  const float* data = (const float*)d_in[0];
  const float* x    = (const float*)d_in[1];
  const int*   ei   = (const int*)d_in[2];
  const float* W1   = (const float*)d_in[3];
  const float* b1   = (const float*)d_in[4];
  const float* W2   = (const float*)d_in[5];
  const float* b2   = (const float*)d_in[6];
  float* out = (float*)d_out;

  char* ws = (char*)d_ws;
  u16*   A    = (u16*)(ws + 0);            // 12.8 MB
  u16*   Hb   = (u16*)(ws + 12800000);     // 12.8 MB
  u16*   h2t  = (u16*)(ws + 25690112);     // 6.4 MB
  u16*   Wt1  = (u16*)(ws + 32090112);
  u16*   Wt2  = (u16*)(ws + 32155648);
  int*   deg  = (int*)(ws + 32172032);
  int*   rowp = (int*)(ws + 32372032);
  int*   cur  = (int*)(ws + 32572048);
  int*   bsum = (int*)(ws + 32772048);
  float* dinv = (float*)(ws + 32772560);
  int*   col  = (int*)(ws + 32972560);     // 3.2 MB
  float* part = (float*)(ws + 36200448);   // 196x1024x64 f32 = 51.4 MB

  const int* srcp = ei;
  const int* dstp = ei + N_EDGES;

  k_prep<<<(N_NODES + HID * GENE + FEAT * HID + 255) / 256, 256, 0, stream>>>(
      deg, W1, Wt1, W2, Wt2);
  k_deg<<<(N_EDGES / 4 + 255) / 256, 256, 0, stream>>>(dstp, deg);
  int nb = (N_NODES + 511) / 512;  // 98
  k_scan1<<<nb, 512, 0, stream>>>(deg, bsum);
  k_scan2<<<1, 128, 0, stream>>>(bsum, nb);
  k_scan3<<<nb, 512, 0, stream>>>(deg, bsum, rowp, cur, dinv);
  k_fill<<<(N_EDGES / 4 + 255) / 256, 256, 0, stream>>>(srcp, dstp, cur, col);

  gemm_lds<true, HID, GENE><<<(N_NODES + 63) / 64, 256, 0, stream>>>(x, Wt1, dinv, A);
  k_agg128<<<N_NODES / 4, 256, 0, stream>>>((const u32*)A, dinv, rowp, col, b1, (u32*)Hb);

  gemm_lds<false, FEAT, HID><<<(N_NODES + 63) / 64, 256, 0, stream>>>(Hb, Wt2, dinv, A);
  k_agg64<<<N_NODES / 4, 256, 0, stream>>>(A, dinv, rowp, col, b2, Hb);

  k_tr<<<(N_NODES + 63) / 64, 256, 0, stream>>>(Hb, h2t);

  final_mfma<<<dim3(16, NCHUNK), 256, 0, stream>>>(data, h2t, part);
  k_red<<<(1024 * FEAT) / 4 / 256, 256, 0, stream>>>(part, out);
}

// Round 12
// 265.036 us; speedup vs baseline: 1.1508x; 1.0374x over previous
//
#include <hip/hip_runtime.h>
#include <hip/hip_bf16.h>
#include <cstdint>

#define N_NODES 50000
#define N_EDGES 800000
#define GENE    256
#define HID     128
#define FEAT    64
#define NCHUNK  98
#define KC      256
#define KSPAN   512

typedef __attribute__((ext_vector_type(8))) short bf16x8;
typedef __attribute__((ext_vector_type(4))) float f32x4;
typedef unsigned short u16;
typedef unsigned int u32;

__device__ __forceinline__ u16 f2b(float f) {
  __hip_bfloat16 h = __float2bfloat16(f);
  return *reinterpret_cast<u16*>(&h);
}
__device__ __forceinline__ float b2f(u16 u) {
  return __uint_as_float(((unsigned)u) << 16);
}
__device__ __forceinline__ float b2f_lo(u32 u) { return __uint_as_float(u << 16); }
__device__ __forceinline__ float b2f_hi(u32 u) { return __uint_as_float(u & 0xffff0000u); }

__device__ __forceinline__ bf16x8 cvt8(float4 f0, float4 f1) {
  bf16x8 a;
  a[0] = (short)f2b(f0.x); a[1] = (short)f2b(f0.y);
  a[2] = (short)f2b(f0.z); a[3] = (short)f2b(f0.w);
  a[4] = (short)f2b(f1.x); a[5] = (short)f2b(f1.y);
  a[6] = (short)f2b(f1.z); a[7] = (short)f2b(f1.w);
  return a;
}

// ---------------- prep: zero deg + build Wt1/Wt2 (bf16 transposed) ----------------

__global__ void k_prep(int* __restrict__ deg,
                       const float* __restrict__ W1, u16* __restrict__ Wt1,
                       const float* __restrict__ W2, u16* __restrict__ Wt2) {
  int i = blockIdx.x * 256 + threadIdx.x;
  if (i < N_NODES) deg[i] = 0;
  int j = i - N_NODES;
  if (j >= 0 && j < HID * GENE) {
    int n = j / GENE, k = j % GENE;
    Wt1[j] = f2b(W1[(size_t)k * HID + n]);
  }
  int j2 = j - HID * GENE;
  if (j2 >= 0 && j2 < FEAT * HID) {
    int n = j2 / HID, k = j2 % HID;
    Wt2[j2] = f2b(W2[(size_t)k * FEAT + n]);
  }
}

// ---------------- degree / CSR build ----------------

__global__ void k_deg(const int* __restrict__ dst, int* __restrict__ deg) {
  int e4 = blockIdx.x * blockDim.x + threadIdx.x;
  if (e4 * 4 < N_EDGES) {
    int4 d = *(const int4*)(dst + e4 * 4);
    atomicAdd(&deg[d.x], 1);
    atomicAdd(&deg[d.y], 1);
    atomicAdd(&deg[d.z], 1);
    atomicAdd(&deg[d.w], 1);
  }
}

__global__ void k_scan1(const int* __restrict__ deg, int* __restrict__ bsum) {
  __shared__ int s[512];
  int t = threadIdx.x;
  int i = blockIdx.x * 512 + t;
  s[t] = (i < N_NODES) ? deg[i] : 0;
  __syncthreads();
  for (int off = 256; off > 0; off >>= 1) {
    if (t < off) s[t] += s[t + off];
    __syncthreads();
  }
  if (t == 0) bsum[blockIdx.x] = s[0];
}

__global__ void k_scan2(int* bsum, int nb) {
  __shared__ int s[128];
  int t = threadIdx.x;
  int v = (t < nb) ? bsum[t] : 0;
  s[t] = v;
  __syncthreads();
  for (int off = 1; off < 128; off <<= 1) {
    int add = (t >= off) ? s[t - off] : 0;
    __syncthreads();
    s[t] += add;
    __syncthreads();
  }
  if (t < nb) bsum[t] = s[t] - v;  // exclusive
}

// scan3: row_ptr, dinv, cursor = row_ptr
__global__ void k_scan3(const int* __restrict__ deg, const int* __restrict__ bsum,
                        int* __restrict__ row_ptr, int* __restrict__ cur,
                        float* __restrict__ dinv) {
  __shared__ int s[512];
  int t = threadIdx.x;
  int i = blockIdx.x * 512 + t;
  int v = (i < N_NODES) ? deg[i] : 0;
  s[t] = v;
  __syncthreads();
  for (int off = 1; off < 512; off <<= 1) {
    int add = (t >= off) ? s[t - off] : 0;
    __syncthreads();
    s[t] += add;
    __syncthreads();
  }
  int incl = s[t] + bsum[blockIdx.x];
  if (i < N_NODES) {
    int rp = incl - v;
    row_ptr[i] = rp;
    cur[i] = rp;
    dinv[i] = rsqrtf((float)(v + 1));
  }
  if (i == N_NODES - 1) row_ptr[N_NODES] = incl;
}

__global__ void k_fill(const int* __restrict__ src, const int* __restrict__ dst,
                       int* __restrict__ cur, int* __restrict__ col) {
  int e4 = blockIdx.x * blockDim.x + threadIdx.x;
  if (e4 * 4 < N_EDGES) {
    int4 d = *(const int4*)(dst + e4 * 4);
    int4 s = *(const int4*)(src + e4 * 4);
    col[atomicAdd(&cur[d.x], 1)] = s.x;
    col[atomicAdd(&cur[d.y], 1)] = s.y;
    col[atomicAdd(&cur[d.z], 1)] = s.z;
    col[atomicAdd(&cur[d.w], 1)] = s.w;
  }
}

// ---- LDS-staged MFMA GEMM: Y[m] = dinv[m]*(X[m] @ W). ----

template<bool F32IN, int NN, int KK>
__global__ __launch_bounds__(256) void gemm_lds(const void* __restrict__ Xv,
                                                const u16* __restrict__ Wt,
                                                const float* __restrict__ dinv,
                                                u16* __restrict__ Y) {
  constexpr int NF = NN / 32;
  constexpr int KU = KK / 8;
  constexpr int UPT = NN * KK / 8 / 256;
  __shared__ u16 wlds[NN * KK];

  int t = threadIdx.x;
  int w = t >> 6, l = t & 63;
  int lm = l & 15, lg = l >> 4;
  int rowhalf = w >> 1, colhalf = w & 1;
  int m0 = blockIdx.x * 64;
  int cb = colhalf * (NN / 2);

#pragma unroll
  for (int i = 0; i < UPT; ++i) {
    int j = t + i * 256;
    int row = j / KU, u = j - row * KU;
    bf16x8 v = *(const bf16x8*)(Wt + j * 8);
    *(bf16x8*)((char*)wlds + row * (KK * 2) + ((u * 16) ^ ((row & 7) << 4))) = v;
  }
  __syncthreads();

  int ra0 = m0 + rowhalf * 32 + lm;
  int ra1 = ra0 + 16;
  int rs0 = (ra0 < N_NODES) ? ra0 : 0;
  int rs1 = (ra1 < N_NODES) ? ra1 : 0;

  f32x4 acc[2][NF] = {};
#pragma unroll
  for (int k0 = 0; k0 < KK; k0 += 32) {
    bf16x8 a0, a1;
    if constexpr (F32IN) {
      const float* x0 = (const float*)Xv + (size_t)rs0 * KK + k0 + lg * 8;
      const float* x1 = (const float*)Xv + (size_t)rs1 * KK + k0 + lg * 8;
      a0 = cvt8(*(const float4*)x0, *(const float4*)(x0 + 4));
      a1 = cvt8(*(const float4*)x1, *(const float4*)(x1 + 4));
    } else {
      a0 = *(const bf16x8*)((const u16*)Xv + (size_t)rs0 * KK + k0 + lg * 8);
      a1 = *(const bf16x8*)((const u16*)Xv + (size_t)rs1 * KK + k0 + lg * 8);
    }
#pragma unroll
    for (int f = 0; f < NF; ++f) {
      int row = cb + f * 16 + lm;
      bf16x8 b = *(const bf16x8*)((char*)wlds + row * (KK * 2) +
                                  (((k0 + lg * 8) * 2) ^ ((row & 7) << 4)));
      acc[0][f] = __builtin_amdgcn_mfma_f32_16x16x32_bf16(a0, b, acc[0][f], 0, 0, 0);
      acc[1][f] = __builtin_amdgcn_mfma_f32_16x16x32_bf16(a1, b, acc[1][f], 0, 0, 0);
    }
  }
#pragma unroll
  for (int rf = 0; rf < 2; ++rf) {
    int mo = m0 + rowhalf * 32 + rf * 16 + lg * 4;
#pragma unroll
    for (int r = 0; r < 4; ++r) {
      int mm = mo + r;
      if (mm < N_NODES) {
        float dv = dinv[mm];
#pragma unroll
        for (int f = 0; f < NF; ++f)
          Y[(size_t)mm * NN + cb + f * 16 + lm] = f2b(acc[rf][f][r] * dv);
      }
    }
  }
}

// ---- agg HID=128: u32 loads, 1 wave/node, 4 nodes/block ----

__global__ __launch_bounds__(256) void k_agg128(
    const u32* __restrict__ Ain, const float* __restrict__ dinv,
    const int* __restrict__ row_ptr, const int* __restrict__ col,
    const float* __restrict__ bias, u32* __restrict__ out) {
  int t = threadIdx.x;
  int node = blockIdx.x * 4 + (t >> 6);
  int l = t & 63;
  float2 bv = *(const float2*)(bias + 2 * l);

  float di = dinv[node];
  int beg = row_ptr[node], end = row_ptr[node + 1];
  u32 us = Ain[(size_t)node * 64 + l];
  float ax = b2f_lo(us), ay = b2f_hi(us);
  int r = beg;
  for (; r + 4 <= end; r += 4) {
    int s0 = col[r], s1 = col[r + 1], s2 = col[r + 2], s3 = col[r + 3];
    u32 u0 = Ain[(size_t)s0 * 64 + l];
    u32 u1 = Ain[(size_t)s1 * 64 + l];
    u32 u2 = Ain[(size_t)s2 * 64 + l];
    u32 u3 = Ain[(size_t)s3 * 64 + l];
    ax += (b2f_lo(u0) + b2f_lo(u1)) + (b2f_lo(u2) + b2f_lo(u3));
    ay += (b2f_hi(u0) + b2f_hi(u1)) + (b2f_hi(u2) + b2f_hi(u3));
  }
  for (; r < end; ++r) {
    u32 u0 = Ain[(size_t)col[r] * 64 + l];
    ax += b2f_lo(u0); ay += b2f_hi(u0);
  }
  float vx = fmaxf(bv.x + di * ax, 0.f);
  float vy = fmaxf(bv.y + di * ay, 0.f);
  out[(size_t)node * 64 + l] = ((u32)f2b(vy) << 16) | (u32)f2b(vx);
}

// ---- agg FEAT=64: u16 loads, 1 wave/node, 4 nodes/block ----

__global__ __launch_bounds__(256) void k_agg64(
    const u16* __restrict__ Ain, const float* __restrict__ dinv,
    const int* __restrict__ row_ptr, const int* __restrict__ col,
    const float* __restrict__ bias, u16* __restrict__ out) {
  int t = threadIdx.x;
  int node = blockIdx.x * 4 + (t >> 6);
  int f = t & 63;
  float bf = bias[f];

  float di = dinv[node];
  int beg = row_ptr[node], end = row_ptr[node + 1];
  float acc = b2f(Ain[(size_t)node * 64 + f]);
  int r = beg;
  for (; r + 4 <= end; r += 4) {
    int s0 = col[r], s1 = col[r + 1], s2 = col[r + 2], s3 = col[r + 3];
    float a0 = b2f(Ain[(size_t)s0 * 64 + f]);
    float a1 = b2f(Ain[(size_t)s1 * 64 + f]);
    float a2 = b2f(Ain[(size_t)s2 * 64 + f]);
    float a3 = b2f(Ain[(size_t)s3 * 64 + f]);
    acc += (a0 + a1) + (a2 + a3);
  }
  for (; r < end; ++r) acc += b2f(Ain[(size_t)col[r] * 64 + f]);
  out[(size_t)node * 64 + f] = f2b(bf + di * acc);
}

// ---------------- transpose h2 -> h2t ----------------

__global__ __launch_bounds__(256) void k_tr(const u16* __restrict__ h2,
                                            u16* __restrict__ h2t) {
  __shared__ u16 tile[64][65];
  int i0 = blockIdx.x * 64;
  int t = threadIdx.x;
  int r = t >> 2, c0 = (t & 3) * 16;
  int i = i0 + r;
#pragma unroll
  for (int j = 0; j < 16; ++j)
    tile[r][c0 + j] = (i < N_NODES) ? h2[(size_t)i * 64 + c0 + j] : (u16)0;
  __syncthreads();
  int io = t & 63, n0 = (t >> 6) * 16;
  int i2 = i0 + io;
  if (i2 < N_NODES) {
#pragma unroll
    for (int j = 0; j < 16; ++j)
      h2t[(size_t)(n0 + j) * N_NODES + i2] = tile[io][n0 + j];
  }
}

// ---- final: each block accumulates TWO KC=256 chunks (same 32KB LDS re-staged)
//      -> partial buffer and red traffic halved. A: unroll-4, 8 loads in flight. ----

__global__ __launch_bounds__(256) void final_mfma(const float* __restrict__ data,
                                                  const u16* __restrict__ h2t,
                                                  float* __restrict__ partial) {
  constexpr int KU = KC / 8;
  __shared__ u16 blds[64 * KC];  // 32 KB

  int t = threadIdx.x;
  int w = t >> 6, l = t & 63;
  int lm = l & 15, lg = l >> 4;
  int m = blockIdx.x * 64 + w * 16 + lm;
  f32x4 acc[4] = {};

  auto bload = [&](int koff, int f) -> bf16x8 {
    int row = f * 16 + lm;
    return *(const bf16x8*)((char*)blds + row * (KC * 2) +
                            ((koff * 2) ^ ((row & 7) << 4)));
  };

#pragma unroll
  for (int half = 0; half < 2; ++half) {
    int kc0 = blockIdx.y * KSPAN + half * KC;
    int klen = N_NODES - kc0; if (klen > KC) klen = KC;

    __syncthreads();  // previous compute done before re-staging
#pragma unroll
    for (int i = 0; i < 64 * KU / 256; ++i) {
      int j = t + i * 256;
      int row = j / KU, u = j - row * KU;
      int kpos = kc0 + u * 8;
      bf16x8 v = {};
      if (kpos + 8 <= N_NODES) v = *(const bf16x8*)(h2t + (size_t)row * N_NODES + kpos);
      *(bf16x8*)((char*)blds + row * (KC * 2) + ((u * 16) ^ ((row & 7) << 4))) = v;
    }
    __syncthreads();

    const float* drow = data + (size_t)m * N_NODES + kc0 + lg * 8;
    int kk = 0;
    for (; kk + 128 <= klen; kk += 128) {
      float4 fa[4][2];
#pragma unroll
      for (int s = 0; s < 4; ++s) {
        fa[s][0] = *(const float4*)(drow + kk + s * 32);
        fa[s][1] = *(const float4*)(drow + kk + s * 32 + 4);
      }
#pragma unroll
      for (int s = 0; s < 4; ++s) {
        bf16x8 a = cvt8(fa[s][0], fa[s][1]);
#pragma unroll
        for (int f = 0; f < 4; ++f)
          acc[f] = __builtin_amdgcn_mfma_f32_16x16x32_bf16(a, bload(kk + s * 32 + lg * 8, f), acc[f], 0, 0, 0);
      }
    }
    for (; kk + 32 <= klen; kk += 32) {
      bf16x8 a = cvt8(*(const float4*)(drow + kk), *(const float4*)(drow + kk + 4));
#pragma unroll
      for (int f = 0; f < 4; ++f)
        acc[f] = __builtin_amdgcn_mfma_f32_16x16x32_bf16(a, bload(kk + lg * 8, f), acc[f], 0, 0, 0);
    }
    if (kk < klen) {  // 16-wide tail (last chunk only); LDS zero-padded
      bool ok = (kk + lg * 8 + 8) <= klen;
      bf16x8 a = {};
      if (ok) a = cvt8(*(const float4*)(drow + kk), *(const float4*)(drow + kk + 4));
#pragma unroll
      for (int f = 0; f < 4; ++f)
        acc[f] = __builtin_amdgcn_mfma_f32_16x16x32_bf16(a, bload(kk + lg * 8, f), acc[f], 0, 0, 0);
    }
  }

  float* pout = partial + (size_t)blockIdx.y * (1024 * FEAT);
  int mo = blockIdx.x * 64 + w * 16 + lg * 4;
#pragma unroll
  for (int f = 0; f < 4; ++f)
#pragma unroll
    for (int r = 0; r < 4; ++r)
      pout[(size_t)(mo + r) * FEAT + f * 16 + lm] = acc[f][r];
}

__global__ __launch_bounds__(256) void k_red(const float* __restrict__ partial,
                                             float* __restrict__ out) {
  int i = blockIdx.x * 256 + threadIdx.x;  // 16384 float4 outputs
  f32x4 s = {};
#pragma unroll
  for (int c = 0; c < NCHUNK; ++c)
    s += *(const f32x4*)(partial + (size_t)c * (1024 * FEAT) + i * 4);
  *(f32x4*)((float*)out + i * 4) = s;
}

// ---------------- launch ----------------

extern "C" void kernel_launch(void* const* d_in, const int* in_sizes, int n_in,
                              void* d_out, int out_size, void* d_ws, size_t ws_size,
                              hipStream_t stream) {
  const float* data = (const float*)d_in[0];
  const float* x    = (const float*)d_in[1];
  const int*   ei   = (const int*)d_in[2];
  const float* W1   = (const float*)d_in[3];
  const float* b1   = (const float*)d_in[4];
  const float* W2   = (const float*)d_in[5];
  const float* b2   = (const float*)d_in[6];
  float* out = (float*)d_out;

  char* ws = (char*)d_ws;
  u16*   A    = (u16*)(ws + 0);            // 12.8 MB
  u16*   Hb   = (u16*)(ws + 12800000);     // 12.8 MB
  u16*   h2t  = (u16*)(ws + 25690112);     // 6.4 MB
  u16*   Wt1  = (u16*)(ws + 32090112);
  u16*   Wt2  = (u16*)(ws + 32155648);
  int*   deg  = (int*)(ws + 32172032);
  int*   rowp = (int*)(ws + 32372032);
  int*   cur  = (int*)(ws + 32572048);
  int*   bsum = (int*)(ws + 32772048);
  float* dinv = (float*)(ws + 32772560);
  int*   col  = (int*)(ws + 32972560);     // 3.2 MB
  float* part = (float*)(ws + 36200448);   // 98x1024x64 f32 = 25.7 MB

  const int* srcp = ei;
  const int* dstp = ei + N_EDGES;

  k_prep<<<(N_NODES + HID * GENE + FEAT * HID + 255) / 256, 256, 0, stream>>>(
      deg, W1, Wt1, W2, Wt2);
  k_deg<<<(N_EDGES / 4 + 255) / 256, 256, 0, stream>>>(dstp, deg);
  int nb = (N_NODES + 511) / 512;  // 98
  k_scan1<<<nb, 512, 0, stream>>>(deg, bsum);
  k_scan2<<<1, 128, 0, stream>>>(bsum, nb);
  k_scan3<<<nb, 512, 0, stream>>>(deg, bsum, rowp, cur, dinv);
  k_fill<<<(N_EDGES / 4 + 255) / 256, 256, 0, stream>>>(srcp, dstp, cur, col);

  gemm_lds<true, HID, GENE><<<(N_NODES + 63) / 64, 256, 0, stream>>>(x, Wt1, dinv, A);
  k_agg128<<<N_NODES / 4, 256, 0, stream>>>((const u32*)A, dinv, rowp, col, b1, (u32*)Hb);

  gemm_lds<false, FEAT, HID><<<(N_NODES + 63) / 64, 256, 0, stream>>>(Hb, Wt2, dinv, A);
  k_agg64<<<N_NODES / 4, 256, 0, stream>>>(A, dinv, rowp, col, b2, Hb);

  k_tr<<<(N_NODES + 63) / 64, 256, 0, stream>>>(Hb, h2t);

  // final: 98 blocks x 2 chunks of 256, accumulated in-register
  final_mfma<<<dim3(16, NCHUNK), 256, 0, stream>>>(data, h2t, part);
  k_red<<<(1024 * FEAT) / 4 / 256, 256, 0, stream>>>(part, out);
}

// Round 13
// 224.095 us; speedup vs baseline: 1.3611x; 1.1827x over previous
//
#include <hip/hip_runtime.h>
#include <hip/hip_bf16.h>
#include <cstdint>

#define N_NODES 50000
#define N_EDGES 800000
#define GENE    256
#define HID     128
#define FEAT    64
#define NCHUNK  98
#define KC      256
#define KSPAN   512
#define NBKT    391      // buckets of 128 nodes: 391*128 = 50048 >= 50000
#define EB      128      // edge blocks
#define EPB     6250     // edges per block: 128*6250 = 800000

typedef __attribute__((ext_vector_type(8))) short bf16x8;
typedef __attribute__((ext_vector_type(4))) float f32x4;
typedef unsigned short u16;
typedef unsigned int u32;

__device__ __forceinline__ u16 f2b(float f) {
  __hip_bfloat16 h = __float2bfloat16(f);
  return *reinterpret_cast<u16*>(&h);
}
__device__ __forceinline__ float b2f(u16 u) {
  return __uint_as_float(((unsigned)u) << 16);
}
__device__ __forceinline__ float b2f_lo(u32 u) { return __uint_as_float(u << 16); }
__device__ __forceinline__ float b2f_hi(u32 u) { return __uint_as_float(u & 0xffff0000u); }

__device__ __forceinline__ bf16x8 cvt8(float4 f0, float4 f1) {
  bf16x8 a;
  a[0] = (short)f2b(f0.x); a[1] = (short)f2b(f0.y);
  a[2] = (short)f2b(f0.z); a[3] = (short)f2b(f0.w);
  a[4] = (short)f2b(f1.x); a[5] = (short)f2b(f1.y);
  a[6] = (short)f2b(f1.z); a[7] = (short)f2b(f1.w);
  return a;
}

// ---------------- prep: build Wt1/Wt2 (bf16 transposed) ----------------

__global__ void k_prep(const float* __restrict__ W1, u16* __restrict__ Wt1,
                       const float* __restrict__ W2, u16* __restrict__ Wt2) {
  int j = blockIdx.x * 256 + threadIdx.x;
  if (j < HID * GENE) {
    int n = j / GENE, k = j % GENE;
    Wt1[j] = f2b(W1[(size_t)k * HID + n]);
  }
  int j2 = j - HID * GENE;
  if (j2 >= 0 && j2 < FEAT * HID) {
    int n = j2 / HID, k = j2 % HID;
    Wt2[j2] = f2b(W2[(size_t)k * FEAT + n]);
  }
}

// ---------------- CSR build via two-level counting sort (no global atomics) ----

// Pass A: per-block LDS bucket histogram -> cntmat[blk][bkt]
__global__ __launch_bounds__(256) void k_hist(const int* __restrict__ dst,
                                              u32* __restrict__ cntmat) {
  __shared__ u32 h[NBKT];
  int t = threadIdx.x;
  for (int i = t; i < NBKT; i += 256) h[i] = 0;
  __syncthreads();
  int e0 = blockIdx.x * EPB;
  for (int i = t; i < EPB; i += 256)
    atomicAdd(&h[dst[e0 + i] >> 7], 1u);
  __syncthreads();
  for (int i = t; i < NBKT; i += 256)
    cntmat[(size_t)blockIdx.x * NBKT + i] = h[i];
}

// Pass B: bucket totals -> exclusive scan -> per-(block,bucket) offsets in place
__global__ __launch_bounds__(512) void k_scanb(u32* __restrict__ cntmat,
                                               u32* __restrict__ bbase,
                                               int* __restrict__ row_ptr) {
  __shared__ u32 s[512];
  int t = threadIdx.x;
  u32 tot = 0;
  if (t < NBKT)
    for (int b = 0; b < EB; ++b) tot += cntmat[(size_t)b * NBKT + t];
  s[t] = tot;
  __syncthreads();
  for (int off = 1; off < 512; off <<= 1) {
    u32 add = (t >= off) ? s[t - off] : 0;
    __syncthreads();
    s[t] += add;
    __syncthreads();
  }
  u32 excl = s[t] - tot;
  if (t < NBKT) {
    bbase[t] = excl;
    u32 run = excl;
    for (int b = 0; b < EB; ++b) {
      u32 c = cntmat[(size_t)b * NBKT + t];
      cntmat[(size_t)b * NBKT + t] = run;
      run += c;
    }
  }
  if (t == 0) { bbase[NBKT] = (u32)N_EDGES; row_ptr[N_NODES] = N_EDGES; }
}

// Pass C: partition edges into bucket-contiguous ebuf; pack (src<<7)|(dst&127)
__global__ __launch_bounds__(256) void k_part(const int* __restrict__ src,
                                              const int* __restrict__ dst,
                                              const u32* __restrict__ offmat,
                                              u32* __restrict__ ebuf) {
  __shared__ u32 curs[NBKT];
  int t = threadIdx.x;
  for (int i = t; i < NBKT; i += 256)
    curs[i] = offmat[(size_t)blockIdx.x * NBKT + i];
  __syncthreads();
  int e0 = blockIdx.x * EPB;
  for (int i = t; i < EPB; i += 256) {
    int d = dst[e0 + i];
    int sc = src[e0 + i];
    u32 pos = atomicAdd(&curs[d >> 7], 1u);
    ebuf[pos] = ((u32)sc << 7) | (u32)(d & 127);
  }
}

// Pass D: per-bucket counting sort -> row_ptr, dinv, col
__global__ __launch_bounds__(256) void k_bsort(const u32* __restrict__ ebuf,
                                               const u32* __restrict__ bbase,
                                               int* __restrict__ row_ptr,
                                               float* __restrict__ dinv,
                                               int* __restrict__ col) {
  __shared__ u32 cnt[128], cur[128], s[128];
  int t = threadIdx.x;
  int b = blockIdx.x;
  int base = (int)bbase[b], end = (int)bbase[b + 1];
  if (t < 128) cnt[t] = 0;
  __syncthreads();
  for (int e = base + t; e < end; e += 256)
    atomicAdd(&cnt[ebuf[e] & 127], 1u);
  __syncthreads();
  if (t < 128) s[t] = cnt[t];
  __syncthreads();
  for (int off = 1; off < 128; off <<= 1) {
    u32 add = 0;
    if (t < 128 && t >= off) add = s[t - off];
    __syncthreads();
    if (t < 128) s[t] += add;
    __syncthreads();
  }
  if (t < 128) {
    u32 excl = s[t] - cnt[t];
    int node = (b << 7) + t;
    if (node < N_NODES) {
      row_ptr[node] = base + (int)excl;
      dinv[node] = rsqrtf((float)(cnt[t] + 1));
    }
    cur[t] = excl;
  }
  __syncthreads();
  for (int e = base + t; e < end; e += 256) {
    u32 v = ebuf[e];
    u32 pos = atomicAdd(&cur[v & 127], 1u);
    col[base + (int)pos] = (int)(v >> 7);
  }
}

// ---- LDS-staged MFMA GEMM: Y[m] = dinv[m]*(X[m] @ W). ----

template<bool F32IN, int NN, int KK>
__global__ __launch_bounds__(256) void gemm_lds(const void* __restrict__ Xv,
                                                const u16* __restrict__ Wt,
                                                const float* __restrict__ dinv,
                                                u16* __restrict__ Y) {
  constexpr int NF = NN / 32;
  constexpr int KU = KK / 8;
  constexpr int UPT = NN * KK / 8 / 256;
  __shared__ u16 wlds[NN * KK];

  int t = threadIdx.x;
  int w = t >> 6, l = t & 63;
  int lm = l & 15, lg = l >> 4;
  int rowhalf = w >> 1, colhalf = w & 1;
  int m0 = blockIdx.x * 64;
  int cb = colhalf * (NN / 2);

#pragma unroll
  for (int i = 0; i < UPT; ++i) {
    int j = t + i * 256;
    int row = j / KU, u = j - row * KU;
    bf16x8 v = *(const bf16x8*)(Wt + j * 8);
    *(bf16x8*)((char*)wlds + row * (KK * 2) + ((u * 16) ^ ((row & 7) << 4))) = v;
  }
  __syncthreads();

  int ra0 = m0 + rowhalf * 32 + lm;
  int ra1 = ra0 + 16;
  int rs0 = (ra0 < N_NODES) ? ra0 : 0;
  int rs1 = (ra1 < N_NODES) ? ra1 : 0;

  f32x4 acc[2][NF] = {};
#pragma unroll
  for (int k0 = 0; k0 < KK; k0 += 32) {
    bf16x8 a0, a1;
    if constexpr (F32IN) {
      const float* x0 = (const float*)Xv + (size_t)rs0 * KK + k0 + lg * 8;
      const float* x1 = (const float*)Xv + (size_t)rs1 * KK + k0 + lg * 8;
      a0 = cvt8(*(const float4*)x0, *(const float4*)(x0 + 4));
      a1 = cvt8(*(const float4*)x1, *(const float4*)(x1 + 4));
    } else {
      a0 = *(const bf16x8*)((const u16*)Xv + (size_t)rs0 * KK + k0 + lg * 8);
      a1 = *(const bf16x8*)((const u16*)Xv + (size_t)rs1 * KK + k0 + lg * 8);
    }
#pragma unroll
    for (int f = 0; f < NF; ++f) {
      int row = cb + f * 16 + lm;
      bf16x8 b = *(const bf16x8*)((char*)wlds + row * (KK * 2) +
                                  (((k0 + lg * 8) * 2) ^ ((row & 7) << 4)));
      acc[0][f] = __builtin_amdgcn_mfma_f32_16x16x32_bf16(a0, b, acc[0][f], 0, 0, 0);
      acc[1][f] = __builtin_amdgcn_mfma_f32_16x16x32_bf16(a1, b, acc[1][f], 0, 0, 0);
    }
  }
#pragma unroll
  for (int rf = 0; rf < 2; ++rf) {
    int mo = m0 + rowhalf * 32 + rf * 16 + lg * 4;
#pragma unroll
    for (int r = 0; r < 4; ++r) {
      int mm = mo + r;
      if (mm < N_NODES) {
        float dv = dinv[mm];
#pragma unroll
        for (int f = 0; f < NF; ++f)
          Y[(size_t)mm * NN + cb + f * 16 + lm] = f2b(acc[rf][f][r] * dv);
      }
    }
  }
}

// ---- agg HID=128: u32 loads, 1 wave/node, 4 nodes/block ----

__global__ __launch_bounds__(256) void k_agg128(
    const u32* __restrict__ Ain, const float* __restrict__ dinv,
    const int* __restrict__ row_ptr, const int* __restrict__ col,
    const float* __restrict__ bias, u32* __restrict__ out) {
  int t = threadIdx.x;
  int node = blockIdx.x * 4 + (t >> 6);
  int l = t & 63;
  float2 bv = *(const float2*)(bias + 2 * l);

  float di = dinv[node];
  int beg = row_ptr[node], end = row_ptr[node + 1];
  u32 us = Ain[(size_t)node * 64 + l];
  float ax = b2f_lo(us), ay = b2f_hi(us);
  int r = beg;
  for (; r + 4 <= end; r += 4) {
    int s0 = col[r], s1 = col[r + 1], s2 = col[r + 2], s3 = col[r + 3];
    u32 u0 = Ain[(size_t)s0 * 64 + l];
    u32 u1 = Ain[(size_t)s1 * 64 + l];
    u32 u2 = Ain[(size_t)s2 * 64 + l];
    u32 u3 = Ain[(size_t)s3 * 64 + l];
    ax += (b2f_lo(u0) + b2f_lo(u1)) + (b2f_lo(u2) + b2f_lo(u3));
    ay += (b2f_hi(u0) + b2f_hi(u1)) + (b2f_hi(u2) + b2f_hi(u3));
  }
  for (; r < end; ++r) {
    u32 u0 = Ain[(size_t)col[r] * 64 + l];
    ax += b2f_lo(u0); ay += b2f_hi(u0);
  }
  float vx = fmaxf(bv.x + di * ax, 0.f);
  float vy = fmaxf(bv.y + di * ay, 0.f);
  out[(size_t)node * 64 + l] = ((u32)f2b(vy) << 16) | (u32)f2b(vx);
}

// ---- agg FEAT=64: u16 loads, 1 wave/node, 4 nodes/block ----

__global__ __launch_bounds__(256) void k_agg64(
    const u16* __restrict__ Ain, const float* __restrict__ dinv,
    const int* __restrict__ row_ptr, const int* __restrict__ col,
    const float* __restrict__ bias, u16* __restrict__ out) {
  int t = threadIdx.x;
  int node = blockIdx.x * 4 + (t >> 6);
  int f = t & 63;
  float bf = bias[f];

  float di = dinv[node];
  int beg = row_ptr[node], end = row_ptr[node + 1];
  float acc = b2f(Ain[(size_t)node * 64 + f]);
  int r = beg;
  for (; r + 4 <= end; r += 4) {
    int s0 = col[r], s1 = col[r + 1], s2 = col[r + 2], s3 = col[r + 3];
    float a0 = b2f(Ain[(size_t)s0 * 64 + f]);
    float a1 = b2f(Ain[(size_t)s1 * 64 + f]);
    float a2 = b2f(Ain[(size_t)s2 * 64 + f]);
    float a3 = b2f(Ain[(size_t)s3 * 64 + f]);
    acc += (a0 + a1) + (a2 + a3);
  }
  for (; r < end; ++r) acc += b2f(Ain[(size_t)col[r] * 64 + f]);
  out[(size_t)node * 64 + f] = f2b(bf + di * acc);
}

// ---------------- transpose h2 -> h2t ----------------

__global__ __launch_bounds__(256) void k_tr(const u16* __restrict__ h2,
                                            u16* __restrict__ h2t) {
  __shared__ u16 tile[64][65];
  int i0 = blockIdx.x * 64;
  int t = threadIdx.x;
  int r = t >> 2, c0 = (t & 3) * 16;
  int i = i0 + r;
#pragma unroll
  for (int j = 0; j < 16; ++j)
    tile[r][c0 + j] = (i < N_NODES) ? h2[(size_t)i * 64 + c0 + j] : (u16)0;
  __syncthreads();
  int io = t & 63, n0 = (t >> 6) * 16;
  int i2 = i0 + io;
  if (i2 < N_NODES) {
#pragma unroll
    for (int j = 0; j < 16; ++j)
      h2t[(size_t)(n0 + j) * N_NODES + i2] = tile[io][n0 + j];
  }
}

// ---- final: 2 chunks of KC=256 per block, same 32KB LDS re-staged ----

__global__ __launch_bounds__(256) void final_mfma(const float* __restrict__ data,
                                                  const u16* __restrict__ h2t,
                                                  float* __restrict__ partial) {
  constexpr int KU = KC / 8;
  __shared__ u16 blds[64 * KC];  // 32 KB

  int t = threadIdx.x;
  int w = t >> 6, l = t & 63;
  int lm = l & 15, lg = l >> 4;
  int m = blockIdx.x * 64 + w * 16 + lm;
  f32x4 acc[4] = {};

  auto bload = [&](int koff, int f) -> bf16x8 {
    int row = f * 16 + lm;
    return *(const bf16x8*)((char*)blds + row * (KC * 2) +
                            ((koff * 2) ^ ((row & 7) << 4)));
  };

#pragma unroll
  for (int half = 0; half < 2; ++half) {
    int kc0 = blockIdx.y * KSPAN + half * KC;
    int klen = N_NODES - kc0; if (klen > KC) klen = KC;

    __syncthreads();
#pragma unroll
    for (int i = 0; i < 64 * KU / 256; ++i) {
      int j = t + i * 256;
      int row = j / KU, u = j - row * KU;
      int kpos = kc0 + u * 8;
      bf16x8 v = {};
      if (kpos + 8 <= N_NODES) v = *(const bf16x8*)(h2t + (size_t)row * N_NODES + kpos);
      *(bf16x8*)((char*)blds + row * (KC * 2) + ((u * 16) ^ ((row & 7) << 4))) = v;
    }
    __syncthreads();

    const float* drow = data + (size_t)m * N_NODES + kc0 + lg * 8;
    int kk = 0;
    for (; kk + 128 <= klen; kk += 128) {
      float4 fa[4][2];
#pragma unroll
      for (int s = 0; s < 4; ++s) {
        fa[s][0] = *(const float4*)(drow + kk + s * 32);
        fa[s][1] = *(const float4*)(drow + kk + s * 32 + 4);
      }
#pragma unroll
      for (int s = 0; s < 4; ++s) {
        bf16x8 a = cvt8(fa[s][0], fa[s][1]);
#pragma unroll
        for (int f = 0; f < 4; ++f)
          acc[f] = __builtin_amdgcn_mfma_f32_16x16x32_bf16(a, bload(kk + s * 32 + lg * 8, f), acc[f], 0, 0, 0);
      }
    }
    for (; kk + 32 <= klen; kk += 32) {
      bf16x8 a = cvt8(*(const float4*)(drow + kk), *(const float4*)(drow + kk + 4));
#pragma unroll
      for (int f = 0; f < 4; ++f)
        acc[f] = __builtin_amdgcn_mfma_f32_16x16x32_bf16(a, bload(kk + lg * 8, f), acc[f], 0, 0, 0);
    }
    if (kk < klen) {
      bool ok = (kk + lg * 8 + 8) <= klen;
      bf16x8 a = {};
      if (ok) a = cvt8(*(const float4*)(drow + kk), *(const float4*)(drow + kk + 4));
#pragma unroll
      for (int f = 0; f < 4; ++f)
        acc[f] = __builtin_amdgcn_mfma_f32_16x16x32_bf16(a, bload(kk + lg * 8, f), acc[f], 0, 0, 0);
    }
  }

  float* pout = partial + (size_t)blockIdx.y * (1024 * FEAT);
  int mo = blockIdx.x * 64 + w * 16 + lg * 4;
#pragma unroll
  for (int f = 0; f < 4; ++f)
#pragma unroll
    for (int r = 0; r < 4; ++r)
      pout[(size_t)(mo + r) * FEAT + f * 16 + lm] = acc[f][r];
}

__global__ __launch_bounds__(256) void k_red(const float* __restrict__ partial,
                                             float* __restrict__ out) {
  int i = blockIdx.x * 256 + threadIdx.x;
  f32x4 s = {};
#pragma unroll
  for (int c = 0; c < NCHUNK; ++c)
    s += *(const f32x4*)(partial + (size_t)c * (1024 * FEAT) + i * 4);
  *(f32x4*)((float*)out + i * 4) = s;
}

// ---------------- launch ----------------

extern "C" void kernel_launch(void* const* d_in, const int* in_sizes, int n_in,
                              void* d_out, int out_size, void* d_ws, size_t ws_size,
                              hipStream_t stream) {
  const float* data = (const float*)d_in[0];
  const float* x    = (const float*)d_in[1];
  const int*   ei   = (const int*)d_in[2];
  const float* W1   = (const float*)d_in[3];
  const float* b1   = (const float*)d_in[4];
  const float* W2   = (const float*)d_in[5];
  const float* b2   = (const float*)d_in[6];
  float* out = (float*)d_out;

  char* ws = (char*)d_ws;
  u16*   A      = (u16*)(ws + 0);            // 12.8 MB
  u16*   Hb     = (u16*)(ws + 12800000);     // 12.8 MB
  u16*   h2t    = (u16*)(ws + 25690112);     // 6.4 MB
  u16*   Wt1    = (u16*)(ws + 32090112);     // 64 KB
  u16*   Wt2    = (u16*)(ws + 32155648);     // 16 KB
  int*   rowp   = (int*)(ws + 32172032);     // 200,016 B
  float* dinv   = (float*)(ws + 32372048);   // 200,000 B
  int*   col    = (int*)(ws + 32572048);     // 3.2 MB
  u32*   ebuf   = (u32*)(ws + 35772048);     // 3.2 MB
  u32*   cntmat = (u32*)(ws + 38972048);     // 128*391*4 = 200,192 B
  u32*   bbase  = (u32*)(ws + 39172240);     // 392*4
  float* part   = (float*)(ws + 39173808);   // 98x1024x64 f32 = 25.7 MB

  const int* srcp = ei;
  const int* dstp = ei + N_EDGES;

  k_prep<<<(HID * GENE + FEAT * HID + 255) / 256, 256, 0, stream>>>(W1, Wt1, W2, Wt2);

  // CSR via counting sort (no global atomics)
  k_hist<<<EB, 256, 0, stream>>>(dstp, cntmat);
  k_scanb<<<1, 512, 0, stream>>>(cntmat, bbase, rowp);
  k_part<<<EB, 256, 0, stream>>>(srcp, dstp, cntmat, ebuf);
  k_bsort<<<NBKT, 256, 0, stream>>>(ebuf, bbase, rowp, dinv, col);

  gemm_lds<true, HID, GENE><<<(N_NODES + 63) / 64, 256, 0, stream>>>(x, Wt1, dinv, A);
  k_agg128<<<N_NODES / 4, 256, 0, stream>>>((const u32*)A, dinv, rowp, col, b1, (u32*)Hb);

  gemm_lds<false, FEAT, HID><<<(N_NODES + 63) / 64, 256, 0, stream>>>(Hb, Wt2, dinv, A);
  k_agg64<<<N_NODES / 4, 256, 0, stream>>>(A, dinv, rowp, col, b2, Hb);

  k_tr<<<(N_NODES + 63) / 64, 256, 0, stream>>>(Hb, h2t);

  final_mfma<<<dim3(16, NCHUNK), 256, 0, stream>>>(data, h2t, part);
  k_red<<<(1024 * FEAT) / 4 / 256, 256, 0, stream>>>(part, out);
}

// Round 14
// 205.240 us; speedup vs baseline: 1.4861x; 1.0919x over previous
//
#include <hip/hip_runtime.h>
#include <hip/hip_bf16.h>
#include <cstdint>

#define N_NODES 50000
#define N_EDGES 800000
#define GENE    256
#define HID     128
#define FEAT    64
#define NCHUNK  98
#define KC      256
#define KSPAN   512
#define NBKT    391      // buckets of 128 nodes: 391*128 = 50048 >= 50000
#define EB      128      // edge blocks
#define EPB     6250     // edges per block: 128*6250 = 800000

typedef __attribute__((ext_vector_type(8))) short bf16x8;
typedef __attribute__((ext_vector_type(4))) float f32x4;
typedef unsigned short u16;
typedef unsigned int u32;

__device__ __forceinline__ u16 f2b(float f) {
  __hip_bfloat16 h = __float2bfloat16(f);
  return *reinterpret_cast<u16*>(&h);
}
__device__ __forceinline__ float b2f(u16 u) {
  return __uint_as_float(((unsigned)u) << 16);
}
__device__ __forceinline__ float b2f_lo(u32 u) { return __uint_as_float(u << 16); }
__device__ __forceinline__ float b2f_hi(u32 u) { return __uint_as_float(u & 0xffff0000u); }

__device__ __forceinline__ bf16x8 cvt8(float4 f0, float4 f1) {
  bf16x8 a;
  a[0] = (short)f2b(f0.x); a[1] = (short)f2b(f0.y);
  a[2] = (short)f2b(f0.z); a[3] = (short)f2b(f0.w);
  a[4] = (short)f2b(f1.x); a[5] = (short)f2b(f1.y);
  a[6] = (short)f2b(f1.z); a[7] = (short)f2b(f1.w);
  return a;
}

// ---- fused: Pass A bucket histogram (blocks 0..EB-1) + Wt build (blocks EB..) ----

__global__ __launch_bounds__(256) void k_prep_hist(
    const int* __restrict__ dst, u32* __restrict__ cntmat,
    const float* __restrict__ W1, u16* __restrict__ Wt1,
    const float* __restrict__ W2, u16* __restrict__ Wt2) {
  __shared__ u32 h[NBKT];
  int t = threadIdx.x;
  if (blockIdx.x < EB) {
    for (int i = t; i < NBKT; i += 256) h[i] = 0;
    __syncthreads();
    int e0 = blockIdx.x * EPB;
    for (int i = t; i < EPB; i += 256)
      atomicAdd(&h[dst[e0 + i] >> 7], 1u);
    __syncthreads();
    for (int i = t; i < NBKT; i += 256)
      cntmat[(size_t)blockIdx.x * NBKT + i] = h[i];
  } else {
    int j = (blockIdx.x - EB) * 256 + t;
    if (j < HID * GENE) {
      int n = j / GENE, k = j % GENE;
      Wt1[j] = f2b(W1[(size_t)k * HID + n]);
    }
    int j2 = j - HID * GENE;
    if (j2 >= 0 && j2 < FEAT * HID) {
      int n = j2 / HID, k = j2 % HID;
      Wt2[j2] = f2b(W2[(size_t)k * FEAT + n]);
    }
  }
}

// Pass B: bucket totals -> exclusive scan -> per-(block,bucket) offsets in place
__global__ __launch_bounds__(512) void k_scanb(u32* __restrict__ cntmat,
                                               u32* __restrict__ bbase,
                                               int* __restrict__ row_ptr) {
  __shared__ u32 s[512];
  int t = threadIdx.x;
  u32 tot = 0;
  if (t < NBKT)
    for (int b = 0; b < EB; ++b) tot += cntmat[(size_t)b * NBKT + t];
  s[t] = tot;
  __syncthreads();
  for (int off = 1; off < 512; off <<= 1) {
    u32 add = (t >= off) ? s[t - off] : 0;
    __syncthreads();
    s[t] += add;
    __syncthreads();
  }
  u32 excl = s[t] - tot;
  if (t < NBKT) {
    bbase[t] = excl;
    u32 run = excl;
    for (int b = 0; b < EB; ++b) {
      u32 c = cntmat[(size_t)b * NBKT + t];
      cntmat[(size_t)b * NBKT + t] = run;
      run += c;
    }
  }
  if (t == 0) { bbase[NBKT] = (u32)N_EDGES; row_ptr[N_NODES] = N_EDGES; }
}

// Pass C: partition edges into bucket-contiguous ebuf; pack (src<<7)|(dst&127)
__global__ __launch_bounds__(256) void k_part(const int* __restrict__ src,
                                              const int* __restrict__ dst,
                                              const u32* __restrict__ offmat,
                                              u32* __restrict__ ebuf) {
  __shared__ u32 curs[NBKT];
  int t = threadIdx.x;
  for (int i = t; i < NBKT; i += 256)
    curs[i] = offmat[(size_t)blockIdx.x * NBKT + i];
  __syncthreads();
  int e0 = blockIdx.x * EPB;
  for (int i = t; i < EPB; i += 256) {
    int d = dst[e0 + i];
    int sc = src[e0 + i];
    u32 pos = atomicAdd(&curs[d >> 7], 1u);
    ebuf[pos] = ((u32)sc << 7) | (u32)(d & 127);
  }
}

// Pass D: per-bucket counting sort -> row_ptr, dinv, col
__global__ __launch_bounds__(256) void k_bsort(const u32* __restrict__ ebuf,
                                               const u32* __restrict__ bbase,
                                               int* __restrict__ row_ptr,
                                               float* __restrict__ dinv,
                                               int* __restrict__ col) {
  __shared__ u32 cnt[128], cur[128], s[128];
  int t = threadIdx.x;
  int b = blockIdx.x;
  int base = (int)bbase[b], end = (int)bbase[b + 1];
  if (t < 128) cnt[t] = 0;
  __syncthreads();
  for (int e = base + t; e < end; e += 256)
    atomicAdd(&cnt[ebuf[e] & 127], 1u);
  __syncthreads();
  if (t < 128) s[t] = cnt[t];
  __syncthreads();
  for (int off = 1; off < 128; off <<= 1) {
    u32 add = 0;
    if (t < 128 && t >= off) add = s[t - off];
    __syncthreads();
    if (t < 128) s[t] += add;
    __syncthreads();
  }
  if (t < 128) {
    u32 excl = s[t] - cnt[t];
    int node = (b << 7) + t;
    if (node < N_NODES) {
      row_ptr[node] = base + (int)excl;
      dinv[node] = rsqrtf((float)(cnt[t] + 1));
    }
    cur[t] = excl;
  }
  __syncthreads();
  for (int e = base + t; e < end; e += 256) {
    u32 v = ebuf[e];
    u32 pos = atomicAdd(&cur[v & 127], 1u);
    col[base + (int)pos] = (int)(v >> 7);
  }
}

// ---- LDS-staged MFMA GEMM: Y[m] = dinv[m]*(X[m] @ W). ----

template<bool F32IN, int NN, int KK>
__global__ __launch_bounds__(256) void gemm_lds(const void* __restrict__ Xv,
                                                const u16* __restrict__ Wt,
                                                const float* __restrict__ dinv,
                                                u16* __restrict__ Y) {
  constexpr int NF = NN / 32;
  constexpr int KU = KK / 8;
  constexpr int UPT = NN * KK / 8 / 256;
  __shared__ u16 wlds[NN * KK];

  int t = threadIdx.x;
  int w = t >> 6, l = t & 63;
  int lm = l & 15, lg = l >> 4;
  int rowhalf = w >> 1, colhalf = w & 1;
  int m0 = blockIdx.x * 64;
  int cb = colhalf * (NN / 2);

#pragma unroll
  for (int i = 0; i < UPT; ++i) {
    int j = t + i * 256;
    int row = j / KU, u = j - row * KU;
    bf16x8 v = *(const bf16x8*)(Wt + j * 8);
    *(bf16x8*)((char*)wlds + row * (KK * 2) + ((u * 16) ^ ((row & 7) << 4))) = v;
  }
  __syncthreads();

  int ra0 = m0 + rowhalf * 32 + lm;
  int ra1 = ra0 + 16;
  int rs0 = (ra0 < N_NODES) ? ra0 : 0;
  int rs1 = (ra1 < N_NODES) ? ra1 : 0;

  f32x4 acc[2][NF] = {};
#pragma unroll
  for (int k0 = 0; k0 < KK; k0 += 32) {
    bf16x8 a0, a1;
    if constexpr (F32IN) {
      const float* x0 = (const float*)Xv + (size_t)rs0 * KK + k0 + lg * 8;
      const float* x1 = (const float*)Xv + (size_t)rs1 * KK + k0 + lg * 8;
      a0 = cvt8(*(const float4*)x0, *(const float4*)(x0 + 4));
      a1 = cvt8(*(const float4*)x1, *(const float4*)(x1 + 4));
    } else {
      a0 = *(const bf16x8*)((const u16*)Xv + (size_t)rs0 * KK + k0 + lg * 8);
      a1 = *(const bf16x8*)((const u16*)Xv + (size_t)rs1 * KK + k0 + lg * 8);
    }
#pragma unroll
    for (int f = 0; f < NF; ++f) {
      int row = cb + f * 16 + lm;
      bf16x8 b = *(const bf16x8*)((char*)wlds + row * (KK * 2) +
                                  (((k0 + lg * 8) * 2) ^ ((row & 7) << 4)));
      acc[0][f] = __builtin_amdgcn_mfma_f32_16x16x32_bf16(a0, b, acc[0][f], 0, 0, 0);
      acc[1][f] = __builtin_amdgcn_mfma_f32_16x16x32_bf16(a1, b, acc[1][f], 0, 0, 0);
    }
  }
#pragma unroll
  for (int rf = 0; rf < 2; ++rf) {
    int mo = m0 + rowhalf * 32 + rf * 16 + lg * 4;
#pragma unroll
    for (int r = 0; r < 4; ++r) {
      int mm = mo + r;
      if (mm < N_NODES) {
        float dv = dinv[mm];
#pragma unroll
        for (int f = 0; f < NF; ++f)
          Y[(size_t)mm * NN + cb + f * 16 + lm] = f2b(acc[rf][f][r] * dv);
      }
    }
  }
}

// ---- agg HID=128: u32 loads, 1 wave/node, 4 nodes/block, unroll-8 ----

__global__ __launch_bounds__(256) void k_agg128(
    const u32* __restrict__ Ain, const float* __restrict__ dinv,
    const int* __restrict__ row_ptr, const int* __restrict__ col,
    const float* __restrict__ bias, u32* __restrict__ out) {
  int t = threadIdx.x;
  int node = blockIdx.x * 4 + (t >> 6);
  int l = t & 63;
  float2 bv = *(const float2*)(bias + 2 * l);

  float di = dinv[node];
  int beg = row_ptr[node], end = row_ptr[node + 1];
  u32 us = Ain[(size_t)node * 64 + l];
  float ax = b2f_lo(us), ay = b2f_hi(us);
  int r = beg;
  for (; r + 8 <= end; r += 8) {
    u32 u0 = Ain[(size_t)col[r]     * 64 + l];
    u32 u1 = Ain[(size_t)col[r + 1] * 64 + l];
    u32 u2 = Ain[(size_t)col[r + 2] * 64 + l];
    u32 u3 = Ain[(size_t)col[r + 3] * 64 + l];
    u32 u4 = Ain[(size_t)col[r + 4] * 64 + l];
    u32 u5 = Ain[(size_t)col[r + 5] * 64 + l];
    u32 u6 = Ain[(size_t)col[r + 6] * 64 + l];
    u32 u7 = Ain[(size_t)col[r + 7] * 64 + l];
    ax += ((b2f_lo(u0) + b2f_lo(u1)) + (b2f_lo(u2) + b2f_lo(u3))) +
          ((b2f_lo(u4) + b2f_lo(u5)) + (b2f_lo(u6) + b2f_lo(u7)));
    ay += ((b2f_hi(u0) + b2f_hi(u1)) + (b2f_hi(u2) + b2f_hi(u3))) +
          ((b2f_hi(u4) + b2f_hi(u5)) + (b2f_hi(u6) + b2f_hi(u7)));
  }
  for (; r + 4 <= end; r += 4) {
    u32 u0 = Ain[(size_t)col[r]     * 64 + l];
    u32 u1 = Ain[(size_t)col[r + 1] * 64 + l];
    u32 u2 = Ain[(size_t)col[r + 2] * 64 + l];
    u32 u3 = Ain[(size_t)col[r + 3] * 64 + l];
    ax += (b2f_lo(u0) + b2f_lo(u1)) + (b2f_lo(u2) + b2f_lo(u3));
    ay += (b2f_hi(u0) + b2f_hi(u1)) + (b2f_hi(u2) + b2f_hi(u3));
  }
  for (; r < end; ++r) {
    u32 u0 = Ain[(size_t)col[r] * 64 + l];
    ax += b2f_lo(u0); ay += b2f_hi(u0);
  }
  float vx = fmaxf(bv.x + di * ax, 0.f);
  float vy = fmaxf(bv.y + di * ay, 0.f);
  out[(size_t)node * 64 + l] = ((u32)f2b(vy) << 16) | (u32)f2b(vx);
}

// ---- agg FEAT=64 fused with transpose: 32 nodes/block (8 per wave),
//      results staged in LDS, written directly to h2t coalesced. ----

__global__ __launch_bounds__(256) void k_agg64t(
    const u16* __restrict__ Ain, const float* __restrict__ dinv,
    const int* __restrict__ row_ptr, const int* __restrict__ col,
    const float* __restrict__ bias, u16* __restrict__ h2t) {
  __shared__ u16 tile[64][34];  // +2 pad: banks spread for col-writes
  int t = threadIdx.x;
  int w = t >> 6, f = t & 63;
  int base = blockIdx.x * 32;
  float bf = bias[f];

  for (int n = 0; n < 8; ++n) {
    int node = base + w * 8 + n;
    if (node < N_NODES) {
      float di = dinv[node];
      int beg = row_ptr[node], end = row_ptr[node + 1];
      float acc = b2f(Ain[(size_t)node * 64 + f]);
      int r = beg;
      for (; r + 8 <= end; r += 8) {
        float a0 = b2f(Ain[(size_t)col[r]     * 64 + f]);
        float a1 = b2f(Ain[(size_t)col[r + 1] * 64 + f]);
        float a2 = b2f(Ain[(size_t)col[r + 2] * 64 + f]);
        float a3 = b2f(Ain[(size_t)col[r + 3] * 64 + f]);
        float a4 = b2f(Ain[(size_t)col[r + 4] * 64 + f]);
        float a5 = b2f(Ain[(size_t)col[r + 5] * 64 + f]);
        float a6 = b2f(Ain[(size_t)col[r + 6] * 64 + f]);
        float a7 = b2f(Ain[(size_t)col[r + 7] * 64 + f]);
        acc += ((a0 + a1) + (a2 + a3)) + ((a4 + a5) + (a6 + a7));
      }
      for (; r + 4 <= end; r += 4) {
        float a0 = b2f(Ain[(size_t)col[r]     * 64 + f]);
        float a1 = b2f(Ain[(size_t)col[r + 1] * 64 + f]);
        float a2 = b2f(Ain[(size_t)col[r + 2] * 64 + f]);
        float a3 = b2f(Ain[(size_t)col[r + 3] * 64 + f]);
        acc += (a0 + a1) + (a2 + a3);
      }
      for (; r < end; ++r) acc += b2f(Ain[(size_t)col[r] * 64 + f]);
      tile[f][w * 8 + n] = f2b(bf + di * acc);
    }
  }
  __syncthreads();

  // write h2t rows: thread t -> row t>>2, 8 cols starting base + (t&3)*8
  int row = t >> 2, cg = t & 3;
  int c0 = base + cg * 8;
  if (c0 + 8 <= N_NODES) {
    u16 tmp[8];
#pragma unroll
    for (int j = 0; j < 8; ++j) tmp[j] = tile[row][cg * 8 + j];
    *(int4*)(h2t + (size_t)row * N_NODES + c0) = *(const int4*)tmp;
  } else {
    for (int j = 0; j < 8 && c0 + j < N_NODES; ++j)
      h2t[(size_t)row * N_NODES + c0 + j] = tile[row][cg * 8 + j];
  }
}

// ---- final: 2 chunks of KC=256 per block, same 32KB LDS re-staged ----

__global__ __launch_bounds__(256) void final_mfma(const float* __restrict__ data,
                                                  const u16* __restrict__ h2t,
                                                  float* __restrict__ partial) {
  constexpr int KU = KC / 8;
  __shared__ u16 blds[64 * KC];  // 32 KB

  int t = threadIdx.x;
  int w = t >> 6, l = t & 63;
  int lm = l & 15, lg = l >> 4;
  int m = blockIdx.x * 64 + w * 16 + lm;
  f32x4 acc[4] = {};

  auto bload = [&](int koff, int f) -> bf16x8 {
    int row = f * 16 + lm;
    return *(const bf16x8*)((char*)blds + row * (KC * 2) +
                            ((koff * 2) ^ ((row & 7) << 4)));
  };

#pragma unroll
  for (int half = 0; half < 2; ++half) {
    int kc0 = blockIdx.y * KSPAN + half * KC;
    int klen = N_NODES - kc0; if (klen > KC) klen = KC;

    __syncthreads();
#pragma unroll
    for (int i = 0; i < 64 * KU / 256; ++i) {
      int j = t + i * 256;
      int row = j / KU, u = j - row * KU;
      int kpos = kc0 + u * 8;
      bf16x8 v = {};
      if (kpos + 8 <= N_NODES) v = *(const bf16x8*)(h2t + (size_t)row * N_NODES + kpos);
      *(bf16x8*)((char*)blds + row * (KC * 2) + ((u * 16) ^ ((row & 7) << 4))) = v;
    }
    __syncthreads();

    const float* drow = data + (size_t)m * N_NODES + kc0 + lg * 8;
    int kk = 0;
    for (; kk + 128 <= klen; kk += 128) {
      float4 fa[4][2];
#pragma unroll
      for (int s = 0; s < 4; ++s) {
        fa[s][0] = *(const float4*)(drow + kk + s * 32);
        fa[s][1] = *(const float4*)(drow + kk + s * 32 + 4);
      }
#pragma unroll
      for (int s = 0; s < 4; ++s) {
        bf16x8 a = cvt8(fa[s][0], fa[s][1]);
#pragma unroll
        for (int f = 0; f < 4; ++f)
          acc[f] = __builtin_amdgcn_mfma_f32_16x16x32_bf16(a, bload(kk + s * 32 + lg * 8, f), acc[f], 0, 0, 0);
      }
    }
    for (; kk + 32 <= klen; kk += 32) {
      bf16x8 a = cvt8(*(const float4*)(drow + kk), *(const float4*)(drow + kk + 4));
#pragma unroll
      for (int f = 0; f < 4; ++f)
        acc[f] = __builtin_amdgcn_mfma_f32_16x16x32_bf16(a, bload(kk + lg * 8, f), acc[f], 0, 0, 0);
    }
    if (kk < klen) {
      bool ok = (kk + lg * 8 + 8) <= klen;
      bf16x8 a = {};
      if (ok) a = cvt8(*(const float4*)(drow + kk), *(const float4*)(drow + kk + 4));
#pragma unroll
      for (int f = 0; f < 4; ++f)
        acc[f] = __builtin_amdgcn_mfma_f32_16x16x32_bf16(a, bload(kk + lg * 8, f), acc[f], 0, 0, 0);
    }
  }

  float* pout = partial + (size_t)blockIdx.y * (1024 * FEAT);
  int mo = blockIdx.x * 64 + w * 16 + lg * 4;
#pragma unroll
  for (int f = 0; f < 4; ++f)
#pragma unroll
    for (int r = 0; r < 4; ++r)
      pout[(size_t)(mo + r) * FEAT + f * 16 + lm] = acc[f][r];
}

__global__ __launch_bounds__(256) void k_red(const float* __restrict__ partial,
                                             float* __restrict__ out) {
  int i = blockIdx.x * 256 + threadIdx.x;
  f32x4 s = {};
#pragma unroll
  for (int c = 0; c < NCHUNK; ++c)
    s += *(const f32x4*)(partial + (size_t)c * (1024 * FEAT) + i * 4);
  *(f32x4*)((float*)out + i * 4) = s;
}

// ---------------- launch ----------------

extern "C" void kernel_launch(void* const* d_in, const int* in_sizes, int n_in,
                              void* d_out, int out_size, void* d_ws, size_t ws_size,
                              hipStream_t stream) {
  const float* data = (const float*)d_in[0];
  const float* x    = (const float*)d_in[1];
  const int*   ei   = (const int*)d_in[2];
  const float* W1   = (const float*)d_in[3];
  const float* b1   = (const float*)d_in[4];
  const float* W2   = (const float*)d_in[5];
  const float* b2   = (const float*)d_in[6];
  float* out = (float*)d_out;

  char* ws = (char*)d_ws;
  u16*   A      = (u16*)(ws + 0);            // 12.8 MB
  u16*   Hb     = (u16*)(ws + 12800000);     // 12.8 MB (h1 only now)
  u16*   h2t    = (u16*)(ws + 25690112);     // 6.4 MB
  u16*   Wt1    = (u16*)(ws + 32090112);     // 64 KB
  u16*   Wt2    = (u16*)(ws + 32155648);     // 16 KB
  int*   rowp   = (int*)(ws + 32172032);
  float* dinv   = (float*)(ws + 32372048);
  int*   col    = (int*)(ws + 32572048);     // 3.2 MB
  u32*   ebuf   = (u32*)(ws + 35772048);     // 3.2 MB
  u32*   cntmat = (u32*)(ws + 38972048);
  u32*   bbase  = (u32*)(ws + 39172240);
  float* part   = (float*)(ws + 39173808);   // 25.7 MB

  const int* srcp = ei;
  const int* dstp = ei + N_EDGES;

  const int PREPB = (HID * GENE + FEAT * HID + 255) / 256;  // 160

  k_prep_hist<<<EB + PREPB, 256, 0, stream>>>(dstp, cntmat, W1, Wt1, W2, Wt2);
  k_scanb<<<1, 512, 0, stream>>>(cntmat, bbase, rowp);
  k_part<<<EB, 256, 0, stream>>>(srcp, dstp, cntmat, ebuf);
  k_bsort<<<NBKT, 256, 0, stream>>>(ebuf, bbase, rowp, dinv, col);

  gemm_lds<true, HID, GENE><<<(N_NODES + 63) / 64, 256, 0, stream>>>(x, Wt1, dinv, A);
  k_agg128<<<N_NODES / 4, 256, 0, stream>>>((const u32*)A, dinv, rowp, col, b1, (u32*)Hb);

  gemm_lds<false, FEAT, HID><<<(N_NODES + 63) / 64, 256, 0, stream>>>(Hb, Wt2, dinv, A);
  // agg64 fused with transpose -> writes h2t directly (Hb no longer needed)
  k_agg64t<<<(N_NODES + 31) / 32, 256, 0, stream>>>(A, dinv, rowp, col, b2, h2t);

  final_mfma<<<dim3(16, NCHUNK), 256, 0, stream>>>(data, h2t, part);
  k_red<<<(1024 * FEAT) / 4 / 256, 256, 0, stream>>>(part, out);
}